// Round 1
// baseline (5554.480 us; speedup 1.0000x reference)
//
#include <hip/hip_runtime.h>
#include <hip/hip_bf16.h>
#include <math.h>

#define N_NODES 50000
#define N_EDGES 400000
#define N_GRAPHS 2500
#define D 128
#define D3 384
#define N_RBF 20
#define R_CUT 5.0f
#define PI_F 3.14159265358979f

__device__ __forceinline__ float silu_f(float x) {
    return x / (1.0f + __expf(-x));
}

// s[n][c] = emb[z[n]][c]
__global__ void k_embed(const int* __restrict__ z, const float* __restrict__ emb,
                        float* __restrict__ s) {
    int i = blockIdx.x * blockDim.x + threadIdx.x;
    if (i < N_NODES * D) {
        int n = i >> 7, c = i & 127;
        s[i] = emb[z[n] * D + c];
    }
}

// s_pass = silu(s @ w1 + b1) @ w2 + b2   (per 16-node tile)
#define K1_NODES 16
__global__ void k_node_msg(const float* __restrict__ s,
                           const float* __restrict__ w1, const float* __restrict__ b1,
                           const float* __restrict__ w2, const float* __restrict__ b2,
                           float* __restrict__ s_pass) {
    __shared__ float s_lds[K1_NODES][D];
    __shared__ float h_lds[K1_NODES][D];
    int base = blockIdx.x * K1_NODES;
    int tid = threadIdx.x; // 256 threads
    for (int i = tid; i < K1_NODES * D; i += 256) {
        int ln = i >> 7, col = i & 127;
        s_lds[ln][col] = s[(size_t)(base + ln) * D + col];
    }
    __syncthreads();
    for (int i = tid; i < K1_NODES * D; i += 256) {
        int ln = i >> 7, col = i & 127;
        float acc = b1[col];
        #pragma unroll 4
        for (int k = 0; k < D; ++k) acc += s_lds[ln][k] * w1[k * D + col];
        h_lds[ln][col] = silu_f(acc);
    }
    __syncthreads();
    for (int i = tid; i < K1_NODES * D3; i += 256) {
        int ln = i / D3, col = i - ln * D3;
        float acc = b2[col];
        #pragma unroll 4
        for (int k = 0; k < D; ++k) acc += h_lds[ln][k] * w2[k * D3 + col];
        s_pass[(size_t)(base + ln) * D3 + col] = acc;
    }
}

// Edge kernel: rbf_fcut * s_pass[src] -> scatter d_s into s, delta_v into vB
#define EPB 2
__global__ void k_edge(const int* __restrict__ edges, const float* __restrict__ r_ij,
                       const float* __restrict__ rhat,
                       const float* __restrict__ rbf_w, const float* __restrict__ rbf_b,
                       const float* __restrict__ s_pass, const float* __restrict__ vA,
                       float* __restrict__ s, float* __restrict__ vB) {
    __shared__ float rbf_lds[EPB][N_RBF];
    int sub = threadIdx.x >> 7;     // edge within block (0..1)
    int c = threadIdx.x & 127;      // channel
    int e = blockIdx.x * EPB + sub; // grid divides N_EDGES exactly
    int dst = edges[e * 2 + 0];
    int src = edges[e * 2 + 1];
    float r = r_ij[e];
    if (c < N_RBF) {
        rbf_lds[sub][c] = __sinf((float)(c + 1) * (PI_F / R_CUT) * r) / r;
    }
    __syncthreads();
    float fc = (r <= R_CUT) ? 0.5f * (__cosf(PI_F * r / R_CUT) + 1.0f) : 0.0f;
    float a0 = rbf_b[c], a1 = rbf_b[D + c], a2 = rbf_b[2 * D + c];
    #pragma unroll
    for (int k = 0; k < N_RBF; ++k) {
        float rv = rbf_lds[sub][k];
        a0 += rv * rbf_w[k * D3 + c];
        a1 += rv * rbf_w[k * D3 + D + c];
        a2 += rv * rbf_w[k * D3 + 2 * D + c];
    }
    const float* sp = s_pass + (size_t)src * D3;
    float dv   = a0 * fc * sp[c];
    float ds   = a1 * fc * sp[D + c];
    float drep = a2 * fc * sp[2 * D + c];
    atomicAdd(&s[(size_t)dst * D + c], ds);
    float rx = rhat[e * 3 + 0], ry = rhat[e * 3 + 1], rz = rhat[e * 3 + 2];
    const float* vsrc = vA + (size_t)src * 3 * D;
    float* vdst = vB + (size_t)dst * 3 * D;
    atomicAdd(&vdst[0 * D + c], vsrc[0 * D + c] * dv + rx * drep);
    atomicAdd(&vdst[1 * D + c], vsrc[1 * D + c] * dv + ry * drep);
    atomicAdd(&vdst[2 * D + c], vsrc[2 * D + c] * dv + rz * drep);
}

// Update kernel: v = vA + vB; U_v, V_v; gated update of s and vA; re-zero vB.
__global__ void k_update(float* __restrict__ s, float* __restrict__ vA, float* __restrict__ vB,
                         const float* __restrict__ U, const float* __restrict__ V,
                         const float* __restrict__ w1, const float* __restrict__ b1,
                         const float* __restrict__ w2, const float* __restrict__ b2) {
    __shared__ float vm[2][3][D];
    __shared__ float sv[2][2 * D];
    __shared__ float h[2][D];
    int sub = threadIdx.x >> 7;
    int c = threadIdx.x & 127;
    int n = blockIdx.x * 2 + sub;   // grid divides N_NODES exactly
    float* vAn = vA + (size_t)n * 3 * D;
    float* vBn = vB + (size_t)n * 3 * D;
    #pragma unroll
    for (int d = 0; d < 3; ++d) {
        float val = vAn[d * D + c] + vBn[d * D + c];
        vm[sub][d][c] = val;
        vBn[d * D + c] = 0.0f;  // reset accumulator for next block iter
    }
    sv[sub][D + c] = s[(size_t)n * D + c];
    __syncthreads();
    float uv[3] = {0.f, 0.f, 0.f}, vv[3] = {0.f, 0.f, 0.f};
    for (int k = 0; k < D; ++k) {
        float u_kc = U[k * D + c];
        float v_kc = V[k * D + c];
        #pragma unroll
        for (int d = 0; d < 3; ++d) {
            uv[d] += vm[sub][d][k] * u_kc;
            vv[d] += vm[sub][d][k] * v_kc;
        }
    }
    float vnorm = sqrtf(vv[0] * vv[0] + vv[1] * vv[1] + vv[2] * vv[2]);
    sv[sub][c] = vnorm;
    __syncthreads();
    float acc = b1[c];
    #pragma unroll 4
    for (int k = 0; k < 2 * D; ++k) acc += sv[sub][k] * w1[k * D + c];
    h[sub][c] = silu_f(acc);
    __syncthreads();
    float a0 = b2[c], a1 = b2[D + c], a2 = b2[2 * D + c];
    #pragma unroll 4
    for (int k = 0; k < D; ++k) {
        float hv = h[sub][k];
        a0 += hv * w2[k * D3 + c];
        a1 += hv * w2[k * D3 + D + c];
        a2 += hv * w2[k * D3 + 2 * D + c];
    }
    float scal = uv[0] * vv[0] + uv[1] * vv[1] + uv[2] * vv[2];
    s[(size_t)n * D + c] = sv[sub][D + c] + scal * a1 + a2;
    #pragma unroll
    for (int d = 0; d < 3; ++d) vAn[d * D + c] = vm[sub][d][c] + a0 * uv[d];
}

// Readout: blue MLP per node, atomic per-graph sum.
__global__ void k_blue(const float* __restrict__ s, const int* __restrict__ graph_idx,
                       const float* __restrict__ w1, const float* __restrict__ b1,
                       const float* __restrict__ w2, const float* __restrict__ b2,
                       float* __restrict__ out) {
    __shared__ float s_lds[D];
    __shared__ float red[2];
    int n = blockIdx.x;
    int c = threadIdx.x; // 128
    s_lds[c] = s[(size_t)n * D + c];
    __syncthreads();
    float acc = b1[c];
    #pragma unroll 4
    for (int k = 0; k < D; ++k) acc += s_lds[k] * w1[k * D + c];
    float val = silu_f(acc) * w2[c];
    #pragma unroll
    for (int off = 32; off > 0; off >>= 1) val += __shfl_down(val, off, 64);
    if ((c & 63) == 0) red[c >> 6] = val;
    __syncthreads();
    if (c == 0) {
        atomicAdd(&out[graph_idx[n]], red[0] + red[1] + b2[0]);
    }
}

extern "C" void kernel_launch(void* const* d_in, const int* in_sizes, int n_in,
                              void* d_out, int out_size, void* d_ws, size_t ws_size,
                              hipStream_t stream) {
    const int*   z         = (const int*)d_in[0];
    const int*   edges     = (const int*)d_in[1];
    const float* r_ij      = (const float*)d_in[2];
    const float* rhat      = (const float*)d_in[3];
    const int*   graph_idx = (const int*)d_in[4];
    const float* emb       = (const float*)d_in[5];
    const float* msg_w1    = (const float*)d_in[6];
    const float* msg_b1    = (const float*)d_in[7];
    const float* msg_w2    = (const float*)d_in[8];
    const float* msg_b2    = (const float*)d_in[9];
    const float* rbf_w     = (const float*)d_in[10];
    const float* rbf_b     = (const float*)d_in[11];
    const float* upd_U     = (const float*)d_in[12];
    const float* upd_V     = (const float*)d_in[13];
    const float* upd_w1    = (const float*)d_in[14];
    const float* upd_b1    = (const float*)d_in[15];
    const float* upd_w2    = (const float*)d_in[16];
    const float* upd_b2    = (const float*)d_in[17];
    const float* blue_w1   = (const float*)d_in[18];
    const float* blue_b1   = (const float*)d_in[19];
    const float* blue_w2   = (const float*)d_in[20];
    const float* blue_b2   = (const float*)d_in[21];
    float* out = (float*)d_out;

    char* ws = (char*)d_ws;
    float* s      = (float*)ws;                               // N*D
    float* vA     = s + (size_t)N_NODES * D;                  // N*3*D
    float* vB     = vA + (size_t)N_NODES * 3 * D;             // N*3*D
    float* s_pass = vB + (size_t)N_NODES * 3 * D;             // N*3*D

    hipMemsetAsync(vA, 0, (size_t)N_NODES * 3 * D * sizeof(float), stream);
    hipMemsetAsync(vB, 0, (size_t)N_NODES * 3 * D * sizeof(float), stream);
    hipMemsetAsync(d_out, 0, (size_t)out_size * sizeof(float), stream);

    k_embed<<<(N_NODES * D) / 256, 256, 0, stream>>>(z, emb, s);

    for (int i = 0; i < 3; ++i) {
        k_node_msg<<<N_NODES / K1_NODES, 256, 0, stream>>>(
            s, msg_w1 + (size_t)i * D * D, msg_b1 + (size_t)i * D,
            msg_w2 + (size_t)i * D * D3, msg_b2 + (size_t)i * D3, s_pass);
        k_edge<<<N_EDGES / EPB, 256, 0, stream>>>(
            edges, r_ij, rhat,
            rbf_w + (size_t)i * N_RBF * D3, rbf_b + (size_t)i * D3,
            s_pass, vA, s, vB);
        k_update<<<N_NODES / 2, 256, 0, stream>>>(
            s, vA, vB,
            upd_U + (size_t)i * D * D, upd_V + (size_t)i * D * D,
            upd_w1 + (size_t)i * 2 * D * D, upd_b1 + (size_t)i * D,
            upd_w2 + (size_t)i * D * D3, upd_b2 + (size_t)i * D3);
    }

    k_blue<<<N_NODES, 128, 0, stream>>>(s, graph_idx, blue_w1, blue_b1, blue_w2, blue_b2, out);
}

// Round 2
// 2856.359 us; speedup vs baseline: 1.9446x; 1.9446x over previous
//
#include <hip/hip_runtime.h>
#include <hip/hip_bf16.h>
#include <math.h>

#define N_NODES 50000
#define N_EDGES 400000
#define N_GRAPHS 2500
#define D 128
#define D3 384
#define N_RBF 20
#define R_CUT 5.0f
#define PI_F 3.14159265358979f

typedef __attribute__((ext_vector_type(8))) short bf16x8;
typedef __attribute__((ext_vector_type(4))) float f32x4;

__device__ __forceinline__ float silu_f(float x) {
    return x / (1.0f + __expf(-x));
}
__device__ __forceinline__ short f2bf(float x) {
    union { float f; unsigned u; } v; v.f = x;
    unsigned r = (v.u + 0x7FFFu + ((v.u >> 16) & 1u)) >> 16;
    return (short)r;
}
__device__ __forceinline__ float bf2f(short x) {
    union { unsigned u; float f; } v; v.u = ((unsigned)(unsigned short)x) << 16;
    return v.f;
}

// ---------------- weight packing: W[K][N] f32 -> fragment-major bf16 ----------------
// P[((nt*NKT+kt)*64+lane)*8+j] = bf16(W[kt*32+(lane>>4)*8+j][nt*16+(lane&15)])
__global__ void k_pack(const float* __restrict__ W, short* __restrict__ P, int K, int N) {
    int t = blockIdx.x * 256 + threadIdx.x;
    int NKT = K / 32;
    int total = (N / 16) * NKT * 64;
    if (t >= total) return;
    int lane = t & 63;
    int kt = (t >> 6) % NKT;
    int nt = (t >> 6) / NKT;
    int k0 = kt * 32 + (lane >> 4) * 8;
    int col = nt * 16 + (lane & 15);
    #pragma unroll
    for (int j = 0; j < 8; ++j)
        P[(size_t)t * 8 + j] = f2bf(W[(size_t)(k0 + j) * N + col]);
}

// ---------------- generic MFMA GEMM: C_bf16[M][N] = act(A[M][K] @ Wp + bias) --------
// AMODE: 0 = A bf16 ; 1 = A f32 ; 2 = split A1 bf16 (k<128) + A2 f32 (k>=128)
template<int K, int N, bool SILU, int AMODE>
__global__ __launch_bounds__(256) void k_gemm(const void* __restrict__ Aptr,
                                              const void* __restrict__ A2ptr,
                                              const short* __restrict__ Bp,
                                              const float* __restrict__ bias,
                                              short* __restrict__ Cbf, int M) {
    constexpr int NKT = K / 32, NNT = N / 16;
    int lane = threadIdx.x & 63, wv = threadIdx.x >> 6;
    int tile = blockIdx.x * 4 + wv;
    if (tile * 16 >= M) return;
    int arow = tile * 16 + (lane & 15);
    int kgrp = (lane >> 4) * 8;

    bf16x8 a[NKT];
    if (AMODE == 0) {
        const short* A = (const short*)Aptr + (size_t)arow * K + kgrp;
        #pragma unroll
        for (int kt = 0; kt < NKT; ++kt) a[kt] = *(const bf16x8*)(A + kt * 32);
    } else if (AMODE == 1) {
        const float* A = (const float*)Aptr + (size_t)arow * K + kgrp;
        #pragma unroll
        for (int kt = 0; kt < NKT; ++kt)
            #pragma unroll
            for (int j = 0; j < 8; ++j) a[kt][j] = f2bf(A[kt * 32 + j]);
    } else {
        const short* A1 = (const short*)Aptr + (size_t)arow * 128 + kgrp;
        const float* A2 = (const float*)A2ptr + (size_t)arow * 128 + kgrp;
        #pragma unroll
        for (int kt = 0; kt < 4 && kt < NKT; ++kt) a[kt] = *(const bf16x8*)(A1 + kt * 32);
        #pragma unroll
        for (int kt = 4; kt < NKT; ++kt)
            #pragma unroll
            for (int j = 0; j < 8; ++j) a[kt][j] = f2bf(A2[(kt - 4) * 32 + j]);
    }

    int crow0 = tile * 16 + (lane >> 4) * 4;
    int ccol = lane & 15;
    const bf16x8* Bv = (const bf16x8*)Bp;
    #pragma unroll
    for (int nt = 0; nt < NNT; ++nt) {
        f32x4 acc = {0.f, 0.f, 0.f, 0.f};
        #pragma unroll
        for (int kt = 0; kt < NKT; ++kt) {
            bf16x8 b = Bv[(nt * NKT + kt) * 64 + lane];
            acc = __builtin_amdgcn_mfma_f32_16x16x32_bf16(a[kt], b, acc, 0, 0, 0);
        }
        int col = nt * 16 + ccol;
        float bs = bias ? bias[col] : 0.0f;
        #pragma unroll
        for (int j = 0; j < 4; ++j) {
            float v = acc[j] + bs;
            if (SILU) v = silu_f(v);
            Cbf[(size_t)(crow0 + j) * N + col] = f2bf(v);
        }
    }
}

// ---------------- embed ----------------
__global__ void k_embed(const int* __restrict__ z, const float* __restrict__ emb,
                        float* __restrict__ s) {
    int i = blockIdx.x * blockDim.x + threadIdx.x;
    if (i < N_NODES * D) {
        int n = i >> 7, c = i & 127;
        s[i] = emb[z[n] * D + c];
    }
}

// ---------------- edge scatter (s_pass bf16) ----------------
#define EPB 2
__global__ void k_edge(const int* __restrict__ edges, const float* __restrict__ r_ij,
                       const float* __restrict__ rhat,
                       const float* __restrict__ rbf_w, const float* __restrict__ rbf_b,
                       const short* __restrict__ s_pass, const float* __restrict__ vA,
                       float* __restrict__ s, float* __restrict__ vB) {
    __shared__ float rbf_lds[EPB][N_RBF];
    int sub = threadIdx.x >> 7;
    int c = threadIdx.x & 127;
    int e = blockIdx.x * EPB + sub;
    int dst = edges[e * 2 + 0];
    int src = edges[e * 2 + 1];
    float r = r_ij[e];
    if (c < N_RBF) {
        rbf_lds[sub][c] = __sinf((float)(c + 1) * (PI_F / R_CUT) * r) / r;
    }
    __syncthreads();
    float fc = (r <= R_CUT) ? 0.5f * (__cosf(PI_F * r / R_CUT) + 1.0f) : 0.0f;
    float a0 = rbf_b[c], a1 = rbf_b[D + c], a2 = rbf_b[2 * D + c];
    #pragma unroll
    for (int k = 0; k < N_RBF; ++k) {
        float rv = rbf_lds[sub][k];
        a0 += rv * rbf_w[k * D3 + c];
        a1 += rv * rbf_w[k * D3 + D + c];
        a2 += rv * rbf_w[k * D3 + 2 * D + c];
    }
    const short* sp = s_pass + (size_t)src * D3;
    float dv   = a0 * fc * bf2f(sp[c]);
    float ds   = a1 * fc * bf2f(sp[D + c]);
    float drep = a2 * fc * bf2f(sp[2 * D + c]);
    atomicAdd(&s[(size_t)dst * D + c], ds);
    float rx = rhat[e * 3 + 0], ry = rhat[e * 3 + 1], rz = rhat[e * 3 + 2];
    const float* vsrc = vA + (size_t)src * 3 * D;
    float* vdst = vB + (size_t)dst * 3 * D;
    atomicAdd(&vdst[0 * D + c], vsrc[0 * D + c] * dv + rx * drep);
    atomicAdd(&vdst[1 * D + c], vsrc[1 * D + c] * dv + ry * drep);
    atomicAdd(&vdst[2 * D + c], vsrc[2 * D + c] * dv + rz * drep);
}

// ---------------- vA += vB ; vm_bf16 = bf16(vA) ----------------
__global__ void k_vmerge(float* __restrict__ vA, const float* __restrict__ vB,
                         short* __restrict__ vm) {
    int i = blockIdx.x * 256 + threadIdx.x;   // over N_NODES*3*D/4
    const float4* a4 = (const float4*)vA;
    const float4* b4 = (const float4*)vB;
    float4 va = a4[i], vb = b4[i];
    va.x += vb.x; va.y += vb.y; va.z += vb.z; va.w += vb.w;
    ((float4*)vA)[i] = va;
    typedef __attribute__((ext_vector_type(4))) short short4v;
    short4v o; o[0] = f2bf(va.x); o[1] = f2bf(va.y); o[2] = f2bf(va.z); o[3] = f2bf(va.w);
    ((short4v*)vm)[i] = o;
}

// ---------------- V_norm from UVv (bf16, cols 128..255 = Vv) ----------------
__global__ void k_svbuild(const short* __restrict__ uvv, short* __restrict__ Vn) {
    int i = blockIdx.x * 256 + threadIdx.x;   // over N_NODES*D
    int n = i >> 7, c = i & 127;
    float acc = 0.f;
    #pragma unroll
    for (int d = 0; d < 3; ++d) {
        float v = bf2f(uvv[(size_t)(n * 3 + d) * 256 + 128 + c]);
        acc += v * v;
    }
    Vn[i] = f2bf(sqrtf(acc));
}

// ---------------- apply gated update ----------------
__global__ void k_apply(float* __restrict__ s, float* __restrict__ vA,
                        const short* __restrict__ uvv, const short* __restrict__ a_bf) {
    int i = blockIdx.x * 256 + threadIdx.x;   // over N_NODES*D
    int n = i >> 7, c = i & 127;
    float avv = bf2f(a_bf[(size_t)n * D3 + c]);
    float asv = bf2f(a_bf[(size_t)n * D3 + D + c]);
    float ass = bf2f(a_bf[(size_t)n * D3 + 2 * D + c]);
    float scal = 0.f;
    float uv[3];
    #pragma unroll
    for (int d = 0; d < 3; ++d) {
        float u = bf2f(uvv[(size_t)(n * 3 + d) * 256 + c]);
        float v = bf2f(uvv[(size_t)(n * 3 + d) * 256 + 128 + c]);
        uv[d] = u;
        scal += u * v;
    }
    s[i] += scal * asv + ass;
    #pragma unroll
    for (int d = 0; d < 3; ++d)
        vA[(size_t)(n * 3 + d) * D + c] += avv * uv[d];
}

// ---------------- readout: dot(h_bf16, blue_w2) + b2 -> atomic per graph ----------------
__global__ void k_blue_dot(const short* __restrict__ h, const int* __restrict__ graph_idx,
                           const float* __restrict__ w2, const float* __restrict__ b2,
                           float* __restrict__ out) {
    __shared__ float red[4];
    int sub = threadIdx.x >> 7;
    int c = threadIdx.x & 127;
    int n = blockIdx.x * 2 + sub;
    float val = bf2f(h[(size_t)n * D + c]) * w2[c];
    #pragma unroll
    for (int off = 32; off > 0; off >>= 1) val += __shfl_down(val, off, 64);
    if ((threadIdx.x & 63) == 0) red[threadIdx.x >> 6] = val;
    __syncthreads();
    if (threadIdx.x == 0)   atomicAdd(&out[graph_idx[n]],     red[0] + red[1] + b2[0]);
    if (threadIdx.x == 128) atomicAdd(&out[graph_idx[n]],     red[2] + red[3] + b2[0]);
}

static inline int gemm_grid(int M) { return (M / 16 + 3) / 4; }

extern "C" void kernel_launch(void* const* d_in, const int* in_sizes, int n_in,
                              void* d_out, int out_size, void* d_ws, size_t ws_size,
                              hipStream_t stream) {
    const int*   z         = (const int*)d_in[0];
    const int*   edges     = (const int*)d_in[1];
    const float* r_ij      = (const float*)d_in[2];
    const float* rhat      = (const float*)d_in[3];
    const int*   graph_idx = (const int*)d_in[4];
    const float* emb       = (const float*)d_in[5];
    const float* msg_w1    = (const float*)d_in[6];
    const float* msg_b1    = (const float*)d_in[7];
    const float* msg_w2    = (const float*)d_in[8];
    const float* msg_b2    = (const float*)d_in[9];
    const float* rbf_w     = (const float*)d_in[10];
    const float* rbf_b     = (const float*)d_in[11];
    const float* upd_U     = (const float*)d_in[12];
    const float* upd_V     = (const float*)d_in[13];
    const float* upd_w1    = (const float*)d_in[14];
    const float* upd_b1    = (const float*)d_in[15];
    const float* upd_w2    = (const float*)d_in[16];
    const float* upd_b2    = (const float*)d_in[17];
    const float* blue_w1   = (const float*)d_in[18];
    const float* blue_b1   = (const float*)d_in[19];
    const float* blue_w2   = (const float*)d_in[20];
    const float* blue_b2   = (const float*)d_in[21];
    float* out = (float*)d_out;

    char* ws = (char*)d_ws;
    size_t off = 0;
    auto alloc = [&](size_t bytes) { void* p = ws + off; off += (bytes + 255) & ~(size_t)255; return p; };

    float* s      = (float*)alloc((size_t)N_NODES * D * 4);           // 25.6 MB
    float* vA     = (float*)alloc((size_t)N_NODES * 3 * D * 4);       // 76.8 MB
    float* vB     = (float*)alloc((size_t)N_NODES * 3 * D * 4);       // 76.8 MB (aliased as UVv bf16)
    short* shrd   = (short*)alloc((size_t)N_NODES * D3 * 2);          // 38.4 MB: s_pass -> vm -> a
    short* hbuf   = (short*)alloc((size_t)N_NODES * D * 2);           // 12.8 MB
    short* Vn     = (short*)alloc((size_t)N_NODES * D * 2);           // 12.8 MB
    short* uvv    = (short*)vB;                                       // [n*3+d][256] bf16

    // packed weights (bf16 fragment-major)
    short* pBlue  = (short*)alloc(16384 * 2);
    short* pMsgW1[3]; short* pMsgW2[3]; short* pUV[3]; short* pUpdW1[3]; short* pUpdW2[3];
    for (int i = 0; i < 3; ++i) {
        pMsgW1[i] = (short*)alloc(16384 * 2);
        pMsgW2[i] = (short*)alloc(49152 * 2);
        pUV[i]    = (short*)alloc(32768 * 2);
        pUpdW1[i] = (short*)alloc(32768 * 2);
        pUpdW2[i] = (short*)alloc(49152 * 2);
    }

    // pack all weights
    auto pack = [&](const float* W, short* P, int K, int N) {
        int total = (N / 16) * (K / 32) * 64;
        k_pack<<<(total + 255) / 256, 256, 0, stream>>>(W, P, K, N);
    };
    pack(blue_w1, pBlue, 128, 128);
    for (int i = 0; i < 3; ++i) {
        pack(msg_w1 + (size_t)i * D * D,      pMsgW1[i], 128, 128);
        pack(msg_w2 + (size_t)i * D * D3,     pMsgW2[i], 128, 384);
        pack(upd_U  + (size_t)i * D * D,      pUV[i],           128, 128);
        pack(upd_V  + (size_t)i * D * D,      pUV[i] + 16384,   128, 128);
        pack(upd_w1 + (size_t)i * 2 * D * D,  pUpdW1[i], 256, 128);
        pack(upd_w2 + (size_t)i * D * D3,     pUpdW2[i], 128, 384);
    }

    hipMemsetAsync(vA, 0, (size_t)N_NODES * 3 * D * 4, stream);
    hipMemsetAsync(vB, 0, (size_t)N_NODES * 3 * D * 4, stream);
    hipMemsetAsync(d_out, 0, (size_t)out_size * sizeof(float), stream);

    k_embed<<<(N_NODES * D) / 256, 256, 0, stream>>>(z, emb, s);

    const int gN  = gemm_grid(N_NODES);       // M = 50000
    const int gN3 = gemm_grid(N_NODES * 3);   // M = 150000

    for (int i = 0; i < 3; ++i) {
        // h = silu(s @ msg_w1 + b1)            [f32 A]
        k_gemm<128, 128, true, 1><<<gN, 256, 0, stream>>>(
            s, nullptr, pMsgW1[i], msg_b1 + (size_t)i * D, hbuf, N_NODES);
        // s_pass = h @ msg_w2 + b2             [bf16 A] -> shrd
        k_gemm<128, 384, false, 0><<<gN, 256, 0, stream>>>(
            hbuf, nullptr, pMsgW2[i], msg_b2 + (size_t)i * D3, shrd, N_NODES);
        // edge scatter
        k_edge<<<N_EDGES / EPB, 256, 0, stream>>>(
            edges, r_ij, rhat,
            rbf_w + (size_t)i * N_RBF * D3, rbf_b + (size_t)i * D3,
            shrd, vA, s, vB);
        // vA += vB ; vm = bf16(vA)  (vm aliases shrd)
        k_vmerge<<<(N_NODES * 3 * D / 4 + 255) / 256, 256, 0, stream>>>(vA, vB, shrd);
        // UVv = vm @ [U|V]   (writes bf16 into vB buffer)
        k_gemm<128, 256, false, 0><<<gN3, 256, 0, stream>>>(
            shrd, nullptr, pUV[i], nullptr, uvv, N_NODES * 3);
        // V_norm
        k_svbuild<<<(N_NODES * D + 255) / 256, 256, 0, stream>>>(uvv, Vn);
        // h2 = silu([Vn | s] @ upd_w1 + b1)    [split A] -> hbuf
        k_gemm<256, 128, true, 2><<<gN, 256, 0, stream>>>(
            Vn, s, pUpdW1[i], upd_b1 + (size_t)i * D, hbuf, N_NODES);
        // a = h2 @ upd_w2 + b2                 [bf16 A] -> shrd
        k_gemm<128, 384, false, 0><<<gN, 256, 0, stream>>>(
            hbuf, nullptr, pUpdW2[i], upd_b2 + (size_t)i * D3, shrd, N_NODES);
        // gated update of s, vA
        k_apply<<<(N_NODES * D + 255) / 256, 256, 0, stream>>>(s, vA, uvv, shrd);
        // re-zero vB for next block's edge scatter
        hipMemsetAsync(vB, 0, (size_t)N_NODES * 3 * D * 4, stream);
    }

    // readout
    k_gemm<128, 128, true, 1><<<gN, 256, 0, stream>>>(
        s, nullptr, pBlue, blue_b1, hbuf, N_NODES);
    k_blue_dot<<<N_NODES / 2, 256, 0, stream>>>(hbuf, graph_idx, blue_w2, blue_b2, out);
}

// Round 3
// 1195.297 us; speedup vs baseline: 4.6469x; 2.3897x over previous
//
#include <hip/hip_runtime.h>
#include <hip/hip_bf16.h>
#include <math.h>

#define N_NODES 50000
#define N_EDGES 400000
#define N_GRAPHS 2500
#define D 128
#define D3 384
#define N_RBF 20
#define R_CUT 5.0f
#define PI_F 3.14159265358979f
#define NCH 98  // ceil(50000/512)

typedef __attribute__((ext_vector_type(8))) short bf16x8;
typedef __attribute__((ext_vector_type(4))) float f32x4;

__device__ __forceinline__ float silu_f(float x) {
    return x / (1.0f + __expf(-x));
}
__device__ __forceinline__ short f2bf(float x) {
    union { float f; unsigned u; } v; v.f = x;
    unsigned r = (v.u + 0x7FFFu + ((v.u >> 16) & 1u)) >> 16;
    return (short)r;
}
__device__ __forceinline__ float bf2f(short x) {
    union { unsigned u; float f; } v; v.u = ((unsigned)(unsigned short)x) << 16;
    return v.f;
}

// ---------------- weight packing: W[K][N] f32 -> fragment-major bf16 ----------------
__global__ void k_pack(const float* __restrict__ W, short* __restrict__ P, int K, int N) {
    int t = blockIdx.x * 256 + threadIdx.x;
    int NKT = K / 32;
    int total = (N / 16) * NKT * 64;
    if (t >= total) return;
    int lane = t & 63;
    int kt = (t >> 6) % NKT;
    int nt = (t >> 6) / NKT;
    int k0 = kt * 32 + (lane >> 4) * 8;
    int col = nt * 16 + (lane & 15);
    #pragma unroll
    for (int j = 0; j < 8; ++j)
        P[(size_t)t * 8 + j] = f2bf(W[(size_t)(k0 + j) * N + col]);
}

// ---------------- generic MFMA GEMM ----------------
// AMODE: 0 = A bf16 ; 1 = A f32 ; 2 = split A1 bf16 (k<128) + A2 f32 (k>=128)
template<int K, int N, bool SILU, int AMODE>
__global__ __launch_bounds__(256) void k_gemm(const void* __restrict__ Aptr,
                                              const void* __restrict__ A2ptr,
                                              const short* __restrict__ Bp,
                                              const float* __restrict__ bias,
                                              short* __restrict__ Cbf, int M) {
    constexpr int NKT = K / 32, NNT = N / 16;
    int lane = threadIdx.x & 63, wv = threadIdx.x >> 6;
    int tile = blockIdx.x * 4 + wv;
    if (tile * 16 >= M) return;
    int arow = tile * 16 + (lane & 15);
    int kgrp = (lane >> 4) * 8;

    bf16x8 a[NKT];
    if (AMODE == 0) {
        const short* A = (const short*)Aptr + (size_t)arow * K + kgrp;
        #pragma unroll
        for (int kt = 0; kt < NKT; ++kt) a[kt] = *(const bf16x8*)(A + kt * 32);
    } else if (AMODE == 1) {
        const float* A = (const float*)Aptr + (size_t)arow * K + kgrp;
        #pragma unroll
        for (int kt = 0; kt < NKT; ++kt)
            #pragma unroll
            for (int j = 0; j < 8; ++j) a[kt][j] = f2bf(A[kt * 32 + j]);
    } else {
        const short* A1 = (const short*)Aptr + (size_t)arow * 128 + kgrp;
        const float* A2 = (const float*)A2ptr + (size_t)arow * 128 + kgrp;
        #pragma unroll
        for (int kt = 0; kt < 4 && kt < NKT; ++kt) a[kt] = *(const bf16x8*)(A1 + kt * 32);
        #pragma unroll
        for (int kt = 4; kt < NKT; ++kt)
            #pragma unroll
            for (int j = 0; j < 8; ++j) a[kt][j] = f2bf(A2[(kt - 4) * 32 + j]);
    }

    int crow0 = tile * 16 + (lane >> 4) * 4;
    int ccol = lane & 15;
    const bf16x8* Bv = (const bf16x8*)Bp;
    #pragma unroll
    for (int nt = 0; nt < NNT; ++nt) {
        f32x4 acc = {0.f, 0.f, 0.f, 0.f};
        #pragma unroll
        for (int kt = 0; kt < NKT; ++kt) {
            bf16x8 b = Bv[(nt * NKT + kt) * 64 + lane];
            acc = __builtin_amdgcn_mfma_f32_16x16x32_bf16(a[kt], b, acc, 0, 0, 0);
        }
        int col = nt * 16 + ccol;
        float bs = bias ? bias[col] : 0.0f;
        #pragma unroll
        for (int j = 0; j < 4; ++j) {
            float v = acc[j] + bs;
            if (SILU) v = silu_f(v);
            Cbf[(size_t)(crow0 + j) * N + col] = f2bf(v);
        }
    }
}

// ---------------- embed ----------------
__global__ void k_embed(const int* __restrict__ z, const float* __restrict__ emb,
                        float* __restrict__ s) {
    int i = blockIdx.x * blockDim.x + threadIdx.x;
    if (i < N_NODES * D) {
        int n = i >> 7, c = i & 127;
        s[i] = emb[z[n] * D + c];
    }
}

// ---------------- edge-sort precompute ----------------
__global__ void k_hist(const int* __restrict__ edges, int* __restrict__ cnt) {
    int e = blockIdx.x * 256 + threadIdx.x;
    if (e < N_EDGES) atomicAdd(&cnt[edges[2 * e]], 1);
}

__global__ void k_scan1(const int* __restrict__ cnt, int* __restrict__ csum) {
    int t = threadIdx.x;                  // 512 threads
    int g = blockIdx.x * 512 + t;
    int v = (g < N_NODES) ? cnt[g] : 0;
    #pragma unroll
    for (int off = 32; off > 0; off >>= 1) v += __shfl_down(v, off, 64);
    __shared__ int ws[8];
    if ((t & 63) == 0) ws[t >> 6] = v;
    __syncthreads();
    if (t == 0) {
        int sum = 0;
        #pragma unroll
        for (int i = 0; i < 8; ++i) sum += ws[i];
        csum[blockIdx.x] = sum;
    }
}

__global__ void k_scan2(const int* __restrict__ csum, int* __restrict__ cbase) {
    if (threadIdx.x == 0 && blockIdx.x == 0) {
        int s = 0;
        for (int i = 0; i < NCH; ++i) { cbase[i] = s; s += csum[i]; }
    }
}

__global__ void k_scan3(const int* __restrict__ cnt, const int* __restrict__ cbase,
                        int* __restrict__ rowptr) {
    __shared__ int buf[512];
    int t = threadIdx.x;
    int g = blockIdx.x * 512 + t;
    int orig = (g < N_NODES) ? cnt[g] : 0;
    buf[t] = orig;
    __syncthreads();
    for (int off = 1; off < 512; off <<= 1) {
        int v = (t >= off) ? buf[t - off] : 0;
        __syncthreads();
        buf[t] += v;
        __syncthreads();
    }
    if (g < N_NODES) rowptr[g] = cbase[blockIdx.x] + buf[t] - orig;
    if (g == 0 && blockIdx.x == 0) rowptr[N_NODES] = N_EDGES;
}

// scatter edges into dst-sorted order + precompute rbf*fc (bf16), fc, rhat
__global__ void k_scatter(const int* __restrict__ edges, const float* __restrict__ r_ij,
                          const float* __restrict__ rhat, const int* __restrict__ rowptr,
                          int* __restrict__ cursor, int* __restrict__ esrc,
                          float4* __restrict__ efr, short* __restrict__ erbf) {
    int e = blockIdx.x * 256 + threadIdx.x;
    if (e >= N_EDGES) return;
    int dst = edges[2 * e], src = edges[2 * e + 1];
    int p = rowptr[dst] + atomicAdd(&cursor[dst], 1);
    esrc[p] = src;
    float r = r_ij[e];
    float fc = (r <= R_CUT) ? 0.5f * (cosf(PI_F * r / R_CUT) + 1.0f) : 0.0f;
    float4 fr;
    fr.x = fc; fr.y = rhat[3 * e]; fr.z = rhat[3 * e + 1]; fr.w = rhat[3 * e + 2];
    efr[p] = fr;
    float inv_r = 1.0f / r;
    #pragma unroll
    for (int k = 0; k < N_RBF; ++k) {
        float rb = sinf((float)(k + 1) * (PI_F / R_CUT) * r) * inv_r;
        erbf[(size_t)p * 24 + k] = f2bf(rb * fc);
    }
}

// ---------------- gather-style edge kernel: one node per 128-thread block ----------------
__global__ __launch_bounds__(128) void k_edge2(
    const int* __restrict__ rowptr, const int* __restrict__ esrc,
    const float4* __restrict__ efr, const short* __restrict__ erbf,
    const float* __restrict__ rbf_w, const float* __restrict__ rbf_b,
    const short* __restrict__ spass, const short* __restrict__ vold,
    float* __restrict__ s, short* __restrict__ vnew) {
    int c = threadIdx.x;  // channel 0..127
    float w0[N_RBF], w1[N_RBF], w2[N_RBF];
    #pragma unroll
    for (int k = 0; k < N_RBF; ++k) {
        w0[k] = rbf_w[k * D3 + c];
        w1[k] = rbf_w[k * D3 + 128 + c];
        w2[k] = rbf_w[k * D3 + 256 + c];
    }
    float b0 = rbf_b[c], b1 = rbf_b[128 + c], b2 = rbf_b[256 + c];
    for (int n = blockIdx.x; n < N_NODES; n += gridDim.x) {
        int p0 = rowptr[n], p1 = rowptr[n + 1];
        float sa = 0.f, va0 = 0.f, va1 = 0.f, va2 = 0.f;
        for (int p = p0; p < p1; ++p) {
            bf16x8 rA = *(const bf16x8*)(erbf + (size_t)p * 24);
            bf16x8 rB = *(const bf16x8*)(erbf + (size_t)p * 24 + 8);
            bf16x8 rC = *(const bf16x8*)(erbf + (size_t)p * 24 + 16);
            float4 fr = efr[p];
            int src = esrc[p];
            float a0 = 0.f, a1 = 0.f, a2 = 0.f;
            #pragma unroll
            for (int k = 0; k < 8; ++k) {
                float rv = bf2f(rA[k]);
                a0 += rv * w0[k]; a1 += rv * w1[k]; a2 += rv * w2[k];
            }
            #pragma unroll
            for (int k = 0; k < 8; ++k) {
                float rv = bf2f(rB[k]);
                a0 += rv * w0[8 + k]; a1 += rv * w1[8 + k]; a2 += rv * w2[8 + k];
            }
            #pragma unroll
            for (int k = 0; k < 4; ++k) {
                float rv = bf2f(rC[k]);
                a0 += rv * w0[16 + k]; a1 += rv * w1[16 + k]; a2 += rv * w2[16 + k];
            }
            a0 += b0 * fr.x; a1 += b1 * fr.x; a2 += b2 * fr.x;
            const short* sp = spass + (size_t)src * D3;
            float dv = a0 * bf2f(sp[c]);
            float ds = a1 * bf2f(sp[128 + c]);
            float dr = a2 * bf2f(sp[256 + c]);
            sa += ds;
            const short* vs = vold + (size_t)src * D3;
            va0 += bf2f(vs[c]) * dv + fr.y * dr;
            va1 += bf2f(vs[128 + c]) * dv + fr.z * dr;
            va2 += bf2f(vs[256 + c]) * dv + fr.w * dr;
        }
        s[(size_t)n * D + c] += sa;
        size_t vb = (size_t)n * D3;
        vnew[vb + c]       = f2bf(bf2f(vold[vb + c]) + va0);
        vnew[vb + 128 + c] = f2bf(bf2f(vold[vb + 128 + c]) + va1);
        vnew[vb + 256 + c] = f2bf(bf2f(vold[vb + 256 + c]) + va2);
    }
}

// ---------------- V_norm ----------------
__global__ void k_svbuild(const short* __restrict__ Vv, short* __restrict__ Vn) {
    int i = blockIdx.x * 256 + threadIdx.x;   // over N_NODES*D
    int n = i >> 7, c = i & 127;
    float acc = 0.f;
    #pragma unroll
    for (int d = 0; d < 3; ++d) {
        float v = bf2f(Vv[(size_t)(n * 3 + d) * D + c]);
        acc += v * v;
    }
    Vn[i] = f2bf(sqrtf(acc));
}

// ---------------- apply gated update (v state in place, bf16) ----------------
__global__ void k_apply(float* __restrict__ s, short* __restrict__ v,
                        const short* __restrict__ Uv, const short* __restrict__ Vv,
                        const short* __restrict__ a_bf) {
    int i = blockIdx.x * 256 + threadIdx.x;   // over N_NODES*D
    int n = i >> 7, c = i & 127;
    float avv = bf2f(a_bf[(size_t)n * D3 + c]);
    float asv = bf2f(a_bf[(size_t)n * D3 + 128 + c]);
    float ass = bf2f(a_bf[(size_t)n * D3 + 256 + c]);
    float scal = 0.f;
    float uvr[3];
    #pragma unroll
    for (int d = 0; d < 3; ++d) {
        float u = bf2f(Uv[(size_t)(n * 3 + d) * D + c]);
        float vv = bf2f(Vv[(size_t)(n * 3 + d) * D + c]);
        uvr[d] = u;
        scal += u * vv;
    }
    s[i] += scal * asv + ass;
    #pragma unroll
    for (int d = 0; d < 3; ++d) {
        size_t idx = (size_t)n * D3 + d * 128 + c;
        v[idx] = f2bf(bf2f(v[idx]) + avv * uvr[d]);
    }
}

// ---------------- readout ----------------
__global__ void k_blue_dot(const short* __restrict__ h, const int* __restrict__ graph_idx,
                           const float* __restrict__ w2, const float* __restrict__ b2,
                           float* __restrict__ out) {
    __shared__ float red[4];
    int c = threadIdx.x & 127;
    int n = blockIdx.x * 2 + (threadIdx.x >> 7);
    float val = bf2f(h[(size_t)n * D + c]) * w2[c];
    #pragma unroll
    for (int off = 32; off > 0; off >>= 1) val += __shfl_down(val, off, 64);
    if ((threadIdx.x & 63) == 0) red[threadIdx.x >> 6] = val;
    __syncthreads();
    if (threadIdx.x == 0)   atomicAdd(&out[graph_idx[n]], red[0] + red[1] + b2[0]);
    if (threadIdx.x == 128) atomicAdd(&out[graph_idx[n]], red[2] + red[3] + b2[0]);
}

static inline int gemm_grid(int M) { return (M / 16 + 3) / 4; }

extern "C" void kernel_launch(void* const* d_in, const int* in_sizes, int n_in,
                              void* d_out, int out_size, void* d_ws, size_t ws_size,
                              hipStream_t stream) {
    const int*   z         = (const int*)d_in[0];
    const int*   edges     = (const int*)d_in[1];
    const float* r_ij      = (const float*)d_in[2];
    const float* rhat      = (const float*)d_in[3];
    const int*   graph_idx = (const int*)d_in[4];
    const float* emb       = (const float*)d_in[5];
    const float* msg_w1    = (const float*)d_in[6];
    const float* msg_b1    = (const float*)d_in[7];
    const float* msg_w2    = (const float*)d_in[8];
    const float* msg_b2    = (const float*)d_in[9];
    const float* rbf_w     = (const float*)d_in[10];
    const float* rbf_b     = (const float*)d_in[11];
    const float* upd_U     = (const float*)d_in[12];
    const float* upd_V     = (const float*)d_in[13];
    const float* upd_w1    = (const float*)d_in[14];
    const float* upd_b1    = (const float*)d_in[15];
    const float* upd_w2    = (const float*)d_in[16];
    const float* upd_b2    = (const float*)d_in[17];
    const float* blue_w1   = (const float*)d_in[18];
    const float* blue_b1   = (const float*)d_in[19];
    const float* blue_w2   = (const float*)d_in[20];
    const float* blue_b2   = (const float*)d_in[21];
    float* out = (float*)d_out;

    char* ws = (char*)d_ws;
    size_t off = 0;
    auto alloc = [&](size_t bytes) { void* p = ws + off; off += (bytes + 255) & ~(size_t)255; return p; };

    float* s      = (float*)alloc((size_t)N_NODES * D * 4);            // 25.6 MB
    short* bufV0  = (short*)alloc((size_t)N_NODES * D3 * 2);           // 38.4 MB (v state / Uv scratch)
    short* bufV1  = (short*)alloc((size_t)N_NODES * D3 * 2);           // 38.4 MB
    short* shrd   = (short*)alloc((size_t)N_NODES * D3 * 2);           // 38.4 MB: s_pass -> a
    short* hbuf   = (short*)alloc((size_t)N_NODES * D * 2);            // 12.8 MB
    short* Vn     = (short*)alloc((size_t)N_NODES * D * 2);            // 12.8 MB
    short* Vv     = (short*)alloc((size_t)N_NODES * D3 * 2);           // 38.4 MB
    // edge tables
    int*    esrc   = (int*)alloc((size_t)N_EDGES * 4);                 // 1.6 MB
    float4* efr    = (float4*)alloc((size_t)N_EDGES * 16);             // 6.4 MB
    short*  erbf   = (short*)alloc((size_t)N_EDGES * 24 * 2);          // 19.2 MB
    int*    rowptr = (int*)alloc((size_t)(N_NODES + 1) * 4);
    int*    cnt    = (int*)alloc((size_t)N_NODES * 4);                 // hist then cursor
    int*    csum   = (int*)alloc(NCH * 4);
    int*    cbase  = (int*)alloc(NCH * 4);

    // packed weights
    short* pBlue = (short*)alloc(16384 * 2);
    short* pMsgW1[3]; short* pMsgW2[3]; short* pU[3]; short* pV[3]; short* pUpdW1[3]; short* pUpdW2[3];
    for (int i = 0; i < 3; ++i) {
        pMsgW1[i] = (short*)alloc(16384 * 2);
        pMsgW2[i] = (short*)alloc(49152 * 2);
        pU[i]     = (short*)alloc(16384 * 2);
        pV[i]     = (short*)alloc(16384 * 2);
        pUpdW1[i] = (short*)alloc(32768 * 2);
        pUpdW2[i] = (short*)alloc(49152 * 2);
    }

    auto pack = [&](const float* W, short* P, int K, int N) {
        int total = (N / 16) * (K / 32) * 64;
        k_pack<<<(total + 255) / 256, 256, 0, stream>>>(W, P, K, N);
    };
    pack(blue_w1, pBlue, 128, 128);
    for (int i = 0; i < 3; ++i) {
        pack(msg_w1 + (size_t)i * D * D,     pMsgW1[i], 128, 128);
        pack(msg_w2 + (size_t)i * D * D3,    pMsgW2[i], 128, 384);
        pack(upd_U  + (size_t)i * D * D,     pU[i],     128, 128);
        pack(upd_V  + (size_t)i * D * D,     pV[i],     128, 128);
        pack(upd_w1 + (size_t)i * 2 * D * D, pUpdW1[i], 256, 128);
        pack(upd_w2 + (size_t)i * D * D3,    pUpdW2[i], 128, 384);
    }

    // ---- edge sort precompute (once per launch) ----
    hipMemsetAsync(cnt, 0, (size_t)N_NODES * 4, stream);
    k_hist<<<(N_EDGES + 255) / 256, 256, 0, stream>>>(edges, cnt);
    k_scan1<<<NCH, 512, 0, stream>>>(cnt, csum);
    k_scan2<<<1, 64, 0, stream>>>(csum, cbase);
    k_scan3<<<NCH, 512, 0, stream>>>(cnt, cbase, rowptr);
    hipMemsetAsync(cnt, 0, (size_t)N_NODES * 4, stream);  // reuse as cursor
    k_scatter<<<(N_EDGES + 255) / 256, 256, 0, stream>>>(edges, r_ij, rhat, rowptr, cnt,
                                                         esrc, efr, erbf);

    // ---- state init ----
    hipMemsetAsync(bufV0, 0, (size_t)N_NODES * D3 * 2, stream);
    hipMemsetAsync(d_out, 0, (size_t)out_size * sizeof(float), stream);
    k_embed<<<(N_NODES * D) / 256, 256, 0, stream>>>(z, emb, s);

    const int gN  = gemm_grid(N_NODES);
    const int gN3 = gemm_grid(N_NODES * 3);

    for (int i = 0; i < 3; ++i) {
        short* vstate = (i & 1) ? bufV1 : bufV0;   // current v (bf16)
        short* vscr   = (i & 1) ? bufV0 : bufV1;   // next v
        // h = silu(s @ msg_w1 + b1)
        k_gemm<128, 128, true, 1><<<gN, 256, 0, stream>>>(
            s, nullptr, pMsgW1[i], msg_b1 + (size_t)i * D, hbuf, N_NODES);
        // s_pass = h @ msg_w2 + b2
        k_gemm<128, 384, false, 0><<<gN, 256, 0, stream>>>(
            hbuf, nullptr, pMsgW2[i], msg_b2 + (size_t)i * D3, shrd, N_NODES);
        // segment-sum edge gather: s += ds ; vscr = vstate + dv
        k_edge2<<<4096, 128, 0, stream>>>(rowptr, esrc, efr, erbf,
                                          rbf_w + (size_t)i * N_RBF * D3,
                                          rbf_b + (size_t)i * D3,
                                          shrd, vstate, s, vscr);
        // Uv = v @ U (into dead vstate buffer) ; Vv = v @ V
        k_gemm<128, 128, false, 0><<<gN3, 256, 0, stream>>>(
            vscr, nullptr, pU[i], nullptr, vstate, N_NODES * 3);
        k_gemm<128, 128, false, 0><<<gN3, 256, 0, stream>>>(
            vscr, nullptr, pV[i], nullptr, Vv, N_NODES * 3);
        // V_norm
        k_svbuild<<<(N_NODES * D) / 256, 256, 0, stream>>>(Vv, Vn);
        // h2 = silu([Vn | s] @ upd_w1 + b1)
        k_gemm<256, 128, true, 2><<<gN, 256, 0, stream>>>(
            Vn, s, pUpdW1[i], upd_b1 + (size_t)i * D, hbuf, N_NODES);
        // a = h2 @ upd_w2 + b2
        k_gemm<128, 384, false, 0><<<gN, 256, 0, stream>>>(
            hbuf, nullptr, pUpdW2[i], upd_b2 + (size_t)i * D3, shrd, N_NODES);
        // gated update of s and v (in place on vscr)
        k_apply<<<(N_NODES * D) / 256, 256, 0, stream>>>(s, vscr, vstate, Vv, shrd);
    }

    // readout
    k_gemm<128, 128, true, 1><<<gN, 256, 0, stream>>>(
        s, nullptr, pBlue, blue_b1, hbuf, N_NODES);
    k_blue_dot<<<N_NODES / 2, 256, 0, stream>>>(hbuf, graph_idx, blue_w2, blue_b2, out);
}

// Round 4
// 1174.130 us; speedup vs baseline: 4.7307x; 1.0180x over previous
//
#include <hip/hip_runtime.h>
#include <hip/hip_bf16.h>
#include <math.h>

#define N_NODES 50000
#define N_EDGES 400000
#define N_GRAPHS 2500
#define D 128
#define D3 384
#define N_RBF 20
#define R_CUT 5.0f
#define PI_F 3.14159265358979f
#define NCH 98  // ceil(50000/512)
#define EPT_STRIDE 24  // f32 per edge: 20 rbf*fc, fc, rhat xyz

typedef __attribute__((ext_vector_type(8))) short bf16x8;
typedef __attribute__((ext_vector_type(4))) float f32x4;

__device__ __forceinline__ float silu_f(float x) {
    return x / (1.0f + __expf(-x));
}
__device__ __forceinline__ short f2bf(float x) {
    union { float f; unsigned u; } v; v.f = x;
    unsigned r = (v.u + 0x7FFFu + ((v.u >> 16) & 1u)) >> 16;
    return (short)r;
}
__device__ __forceinline__ float bf2f(short x) {
    union { unsigned u; float f; } v; v.u = ((unsigned)(unsigned short)x) << 16;
    return v.f;
}

// ---------------- all weight packs in ONE dispatch ----------------
#define MAXJOBS 19
struct PackJobs {
    const float* W[MAXJOBS];
    short* P[MAXJOBS];
    int K[MAXJOBS];
    int N[MAXJOBS];
    int boff[MAXJOBS + 1];
    int njobs;
};
__global__ void k_packall(PackJobs jobs) {
    int b = blockIdx.x;
    int j = 0;
    while (j + 1 < jobs.njobs && b >= jobs.boff[j + 1]) ++j;
    int t = (b - jobs.boff[j]) * 256 + threadIdx.x;
    int K = jobs.K[j], N = jobs.N[j];
    int NKT = K / 32;
    int total = (N / 16) * NKT * 64;
    if (t >= total) return;
    const float* W = jobs.W[j];
    short* P = jobs.P[j];
    int lane = t & 63;
    int kt = (t >> 6) % NKT;
    int nt = (t >> 6) / NKT;
    int k0 = kt * 32 + (lane >> 4) * 8;
    int col = nt * 16 + (lane & 15);
    #pragma unroll
    for (int q = 0; q < 8; ++q)
        P[(size_t)t * 8 + q] = f2bf(W[(size_t)(k0 + q) * N + col]);
}

// ---------------- generic MFMA GEMM ----------------
// AMODE: 0 = A bf16 ; 1 = A f32 ; 2 = split A1 bf16 (k<128) + A2 f32 (k>=128)
template<int K, int N, bool SILU, int AMODE>
__global__ __launch_bounds__(256) void k_gemm(const void* __restrict__ Aptr,
                                              const void* __restrict__ A2ptr,
                                              const short* __restrict__ Bp,
                                              const float* __restrict__ bias,
                                              short* __restrict__ Cbf, int M) {
    constexpr int NKT = K / 32, NNT = N / 16;
    int lane = threadIdx.x & 63, wv = threadIdx.x >> 6;
    int tile = blockIdx.x * 4 + wv;
    if (tile * 16 >= M) return;
    int arow = tile * 16 + (lane & 15);
    int kgrp = (lane >> 4) * 8;

    bf16x8 a[NKT];
    if (AMODE == 0) {
        const short* A = (const short*)Aptr + (size_t)arow * K + kgrp;
        #pragma unroll
        for (int kt = 0; kt < NKT; ++kt) a[kt] = *(const bf16x8*)(A + kt * 32);
    } else if (AMODE == 1) {
        const float* A = (const float*)Aptr + (size_t)arow * K + kgrp;
        #pragma unroll
        for (int kt = 0; kt < NKT; ++kt)
            #pragma unroll
            for (int j = 0; j < 8; ++j) a[kt][j] = f2bf(A[kt * 32 + j]);
    } else {
        const short* A1 = (const short*)Aptr + (size_t)arow * 128 + kgrp;
        const float* A2 = (const float*)A2ptr + (size_t)arow * 128 + kgrp;
        #pragma unroll
        for (int kt = 0; kt < 4 && kt < NKT; ++kt) a[kt] = *(const bf16x8*)(A1 + kt * 32);
        #pragma unroll
        for (int kt = 4; kt < NKT; ++kt)
            #pragma unroll
            for (int j = 0; j < 8; ++j) a[kt][j] = f2bf(A2[(kt - 4) * 32 + j]);
    }

    int crow0 = tile * 16 + (lane >> 4) * 4;
    int ccol = lane & 15;
    const bf16x8* Bv = (const bf16x8*)Bp;
    #pragma unroll
    for (int nt = 0; nt < NNT; ++nt) {
        f32x4 acc = {0.f, 0.f, 0.f, 0.f};
        #pragma unroll
        for (int kt = 0; kt < NKT; ++kt) {
            bf16x8 b = Bv[(nt * NKT + kt) * 64 + lane];
            acc = __builtin_amdgcn_mfma_f32_16x16x32_bf16(a[kt], b, acc, 0, 0, 0);
        }
        int col = nt * 16 + ccol;
        float bs = bias ? bias[col] : 0.0f;
        #pragma unroll
        for (int j = 0; j < 4; ++j) {
            float v = acc[j] + bs;
            if (SILU) v = silu_f(v);
            Cbf[(size_t)(crow0 + j) * N + col] = f2bf(v);
        }
    }
}

// ---------------- embed ----------------
__global__ void k_embed(const int* __restrict__ z, const float* __restrict__ emb,
                        float* __restrict__ s) {
    int i = blockIdx.x * blockDim.x + threadIdx.x;
    if (i < N_NODES * D) {
        int n = i >> 7, c = i & 127;
        s[i] = emb[z[n] * D + c];
    }
}

// ---------------- edge-sort precompute ----------------
__global__ void k_hist(const int* __restrict__ edges, int* __restrict__ cnt) {
    int e = blockIdx.x * 256 + threadIdx.x;
    if (e < N_EDGES) atomicAdd(&cnt[edges[2 * e]], 1);
}

__global__ void k_scan1(const int* __restrict__ cnt, int* __restrict__ csum) {
    int t = threadIdx.x;                  // 512 threads
    int g = blockIdx.x * 512 + t;
    int v = (g < N_NODES) ? cnt[g] : 0;
    #pragma unroll
    for (int off = 32; off > 0; off >>= 1) v += __shfl_down(v, off, 64);
    __shared__ int ws[8];
    if ((t & 63) == 0) ws[t >> 6] = v;
    __syncthreads();
    if (t == 0) {
        int sum = 0;
        #pragma unroll
        for (int i = 0; i < 8; ++i) sum += ws[i];
        csum[blockIdx.x] = sum;
    }
}

__global__ void k_scan2(const int* __restrict__ csum, int* __restrict__ cbase) {
    if (threadIdx.x == 0 && blockIdx.x == 0) {
        int s = 0;
        for (int i = 0; i < NCH; ++i) { cbase[i] = s; s += csum[i]; }
    }
}

__global__ void k_scan3(const int* __restrict__ cnt, const int* __restrict__ cbase,
                        int* __restrict__ rowptr) {
    __shared__ int buf[512];
    int t = threadIdx.x;
    int g = blockIdx.x * 512 + t;
    int orig = (g < N_NODES) ? cnt[g] : 0;
    buf[t] = orig;
    __syncthreads();
    for (int off = 1; off < 512; off <<= 1) {
        int v = (t >= off) ? buf[t - off] : 0;
        __syncthreads();
        buf[t] += v;
        __syncthreads();
    }
    if (g < N_NODES) rowptr[g] = cbase[blockIdx.x] + buf[t] - orig;
    if (g == 0 && blockIdx.x == 0) rowptr[N_NODES] = N_EDGES;
}

// scatter edges into dst-sorted order; per-edge record: 20x rbf*fc (f32), fc, rhat
__global__ void k_scatter(const int* __restrict__ edges, const float* __restrict__ r_ij,
                          const float* __restrict__ rhat, const int* __restrict__ rowptr,
                          int* __restrict__ cursor, int* __restrict__ esrc,
                          float* __restrict__ ept) {
    int e = blockIdx.x * 256 + threadIdx.x;
    if (e >= N_EDGES) return;
    int dst = edges[2 * e], src = edges[2 * e + 1];
    int p = rowptr[dst] + atomicAdd(&cursor[dst], 1);
    esrc[p] = src;
    float r = r_ij[e];
    float fc = (r <= R_CUT) ? 0.5f * (cosf(PI_F * r / R_CUT) + 1.0f) : 0.0f;
    float inv_r = 1.0f / r;
    float* rec = ept + (size_t)p * EPT_STRIDE;
    #pragma unroll
    for (int k = 0; k < N_RBF; ++k) {
        float rb = sinf((float)(k + 1) * (PI_F / R_CUT) * r) * inv_r;
        rec[k] = rb * fc;
    }
    rec[20] = fc;
    rec[21] = rhat[3 * e];
    rec[22] = rhat[3 * e + 1];
    rec[23] = rhat[3 * e + 2];
}

// ---------------- gather-style edge kernel: one node per 128-thread block ----------------
__global__ __launch_bounds__(128, 4) void k_edge2(
    const int* __restrict__ rowptr, const int* __restrict__ esrc,
    const float* __restrict__ ept,
    const float* __restrict__ rbf_w, const float* __restrict__ rbf_b,
    const short* __restrict__ spass, const short* __restrict__ vold,
    float* __restrict__ s, short* __restrict__ vnew) {
    int c = threadIdx.x;  // channel 0..127
    float w0[N_RBF], w1[N_RBF], w2[N_RBF];
    #pragma unroll
    for (int k = 0; k < N_RBF; ++k) {
        w0[k] = rbf_w[k * D3 + c];
        w1[k] = rbf_w[k * D3 + 128 + c];
        w2[k] = rbf_w[k * D3 + 256 + c];
    }
    float b0 = rbf_b[c], b1 = rbf_b[128 + c], b2 = rbf_b[256 + c];
    for (int n = blockIdx.x; n < N_NODES; n += gridDim.x) {
        int p0 = rowptr[n], p1 = rowptr[n + 1];
        float sa = 0.f, va0 = 0.f, va1 = 0.f, va2 = 0.f;
        for (int p = p0; p < p1; ++p) {
            const float4* e4 = (const float4*)(ept + (size_t)p * EPT_STRIDE);
            float4 q0 = e4[0], q1 = e4[1], q2 = e4[2], q3 = e4[3], q4 = e4[4], q5 = e4[5];
            int src = esrc[p];
            float a0, a1, a2;
            float fc = q5.x;
            a0 = b0 * fc; a1 = b1 * fc; a2 = b2 * fc;
            float rv[20] = {q0.x, q0.y, q0.z, q0.w, q1.x, q1.y, q1.z, q1.w,
                            q2.x, q2.y, q2.z, q2.w, q3.x, q3.y, q3.z, q3.w,
                            q4.x, q4.y, q4.z, q4.w};
            #pragma unroll
            for (int k = 0; k < N_RBF; ++k) {
                a0 += rv[k] * w0[k];
                a1 += rv[k] * w1[k];
                a2 += rv[k] * w2[k];
            }
            const short* sp = spass + (size_t)src * D3;
            float dv = a0 * bf2f(sp[c]);
            float ds = a1 * bf2f(sp[128 + c]);
            float dr = a2 * bf2f(sp[256 + c]);
            sa += ds;
            const short* vs = vold + (size_t)src * D3;
            va0 += bf2f(vs[c]) * dv + q5.y * dr;
            va1 += bf2f(vs[128 + c]) * dv + q5.z * dr;
            va2 += bf2f(vs[256 + c]) * dv + q5.w * dr;
        }
        s[(size_t)n * D + c] += sa;
        size_t vb = (size_t)n * D3;
        vnew[vb + c]       = f2bf(bf2f(vold[vb + c]) + va0);
        vnew[vb + 128 + c] = f2bf(bf2f(vold[vb + 128 + c]) + va1);
        vnew[vb + 256 + c] = f2bf(bf2f(vold[vb + 256 + c]) + va2);
    }
}

// ---------------- V_norm ----------------
__global__ void k_svbuild(const short* __restrict__ Vv, short* __restrict__ Vn) {
    int i = blockIdx.x * 256 + threadIdx.x;   // over N_NODES*D
    int n = i >> 7, c = i & 127;
    float acc = 0.f;
    #pragma unroll
    for (int d = 0; d < 3; ++d) {
        float v = bf2f(Vv[(size_t)(n * 3 + d) * D + c]);
        acc += v * v;
    }
    Vn[i] = f2bf(sqrtf(acc));
}

// ---------------- apply gated update (v state in place, bf16) ----------------
__global__ void k_apply(float* __restrict__ s, short* __restrict__ v,
                        const short* __restrict__ Uv, const short* __restrict__ Vv,
                        const short* __restrict__ a_bf) {
    int i = blockIdx.x * 256 + threadIdx.x;   // over N_NODES*D
    int n = i >> 7, c = i & 127;
    float avv = bf2f(a_bf[(size_t)n * D3 + c]);
    float asv = bf2f(a_bf[(size_t)n * D3 + 128 + c]);
    float ass = bf2f(a_bf[(size_t)n * D3 + 256 + c]);
    float scal = 0.f;
    float uvr[3];
    #pragma unroll
    for (int d = 0; d < 3; ++d) {
        float u = bf2f(Uv[(size_t)(n * 3 + d) * D + c]);
        float vv = bf2f(Vv[(size_t)(n * 3 + d) * D + c]);
        uvr[d] = u;
        scal += u * vv;
    }
    s[i] += scal * asv + ass;
    #pragma unroll
    for (int d = 0; d < 3; ++d) {
        size_t idx = (size_t)n * D3 + d * 128 + c;
        v[idx] = f2bf(bf2f(v[idx]) + avv * uvr[d]);
    }
}

// ---------------- readout ----------------
__global__ void k_blue_dot(const short* __restrict__ h, const int* __restrict__ graph_idx,
                           const float* __restrict__ w2, const float* __restrict__ b2,
                           float* __restrict__ out) {
    __shared__ float red[4];
    int c = threadIdx.x & 127;
    int n = blockIdx.x * 2 + (threadIdx.x >> 7);
    float val = bf2f(h[(size_t)n * D + c]) * w2[c];
    #pragma unroll
    for (int off = 32; off > 0; off >>= 1) val += __shfl_down(val, off, 64);
    if ((threadIdx.x & 63) == 0) red[threadIdx.x >> 6] = val;
    __syncthreads();
    if (threadIdx.x == 0)   atomicAdd(&out[graph_idx[n]], red[0] + red[1] + b2[0]);
    if (threadIdx.x == 128) atomicAdd(&out[graph_idx[n]], red[2] + red[3] + b2[0]);
}

static inline int gemm_grid(int M) { return (M / 16 + 3) / 4; }

extern "C" void kernel_launch(void* const* d_in, const int* in_sizes, int n_in,
                              void* d_out, int out_size, void* d_ws, size_t ws_size,
                              hipStream_t stream) {
    const int*   z         = (const int*)d_in[0];
    const int*   edges     = (const int*)d_in[1];
    const float* r_ij      = (const float*)d_in[2];
    const float* rhat      = (const float*)d_in[3];
    const int*   graph_idx = (const int*)d_in[4];
    const float* emb       = (const float*)d_in[5];
    const float* msg_w1    = (const float*)d_in[6];
    const float* msg_b1    = (const float*)d_in[7];
    const float* msg_w2    = (const float*)d_in[8];
    const float* msg_b2    = (const float*)d_in[9];
    const float* rbf_w     = (const float*)d_in[10];
    const float* rbf_b     = (const float*)d_in[11];
    const float* upd_U     = (const float*)d_in[12];
    const float* upd_V     = (const float*)d_in[13];
    const float* upd_w1    = (const float*)d_in[14];
    const float* upd_b1    = (const float*)d_in[15];
    const float* upd_w2    = (const float*)d_in[16];
    const float* upd_b2    = (const float*)d_in[17];
    const float* blue_w1   = (const float*)d_in[18];
    const float* blue_b1   = (const float*)d_in[19];
    const float* blue_w2   = (const float*)d_in[20];
    const float* blue_b2   = (const float*)d_in[21];
    float* out = (float*)d_out;

    char* ws = (char*)d_ws;
    size_t off = 0;
    auto alloc = [&](size_t bytes) { void* p = ws + off; off += (bytes + 255) & ~(size_t)255; return p; };

    float* s      = (float*)alloc((size_t)N_NODES * D * 4);            // 25.6 MB
    short* bufV0  = (short*)alloc((size_t)N_NODES * D3 * 2);           // 38.4 MB
    short* bufV1  = (short*)alloc((size_t)N_NODES * D3 * 2);           // 38.4 MB
    short* shrd   = (short*)alloc((size_t)N_NODES * D3 * 2);           // 38.4 MB: s_pass -> Vn -> a
    short* hbuf   = (short*)alloc((size_t)N_NODES * D * 2);            // 12.8 MB
    short* Vv     = (short*)alloc((size_t)N_NODES * D3 * 2);           // 38.4 MB
    short* Vn     = shrd;   // aliases shrd: s_pass dead when Vn written, a written after Vn consumed
    // edge tables
    int*    esrc   = (int*)alloc((size_t)N_EDGES * 4);                 // 1.6 MB
    float*  ept    = (float*)alloc((size_t)N_EDGES * EPT_STRIDE * 4);  // 38.4 MB
    int*    rowptr = (int*)alloc((size_t)(N_NODES + 1) * 4);
    int*    cnt    = (int*)alloc((size_t)N_NODES * 4);                 // hist then cursor
    int*    csum   = (int*)alloc(NCH * 4);
    int*    cbase  = (int*)alloc(NCH * 4);

    // packed weights
    short* pBlue = (short*)alloc(16384 * 2);
    short* pMsgW1[3]; short* pMsgW2[3]; short* pU[3]; short* pV[3]; short* pUpdW1[3]; short* pUpdW2[3];
    for (int i = 0; i < 3; ++i) {
        pMsgW1[i] = (short*)alloc(16384 * 2);
        pMsgW2[i] = (short*)alloc(49152 * 2);
        pU[i]     = (short*)alloc(16384 * 2);
        pV[i]     = (short*)alloc(16384 * 2);
        pUpdW1[i] = (short*)alloc(32768 * 2);
        pUpdW2[i] = (short*)alloc(49152 * 2);
    }

    // ---- all packs in one dispatch ----
    PackJobs jobs;
    jobs.njobs = 0;
    int bacc = 0;
    auto addjob = [&](const float* W, short* P, int K, int N) {
        int j = jobs.njobs++;
        jobs.W[j] = W; jobs.P[j] = P; jobs.K[j] = K; jobs.N[j] = N;
        jobs.boff[j] = bacc;
        int total = (N / 16) * (K / 32) * 64;
        bacc += (total + 255) / 256;
        jobs.boff[j + 1] = bacc;
    };
    addjob(blue_w1, pBlue, 128, 128);
    for (int i = 0; i < 3; ++i) {
        addjob(msg_w1 + (size_t)i * D * D,     pMsgW1[i], 128, 128);
        addjob(msg_w2 + (size_t)i * D * D3,    pMsgW2[i], 128, 384);
        addjob(upd_U  + (size_t)i * D * D,     pU[i],     128, 128);
        addjob(upd_V  + (size_t)i * D * D,     pV[i],     128, 128);
        addjob(upd_w1 + (size_t)i * 2 * D * D, pUpdW1[i], 256, 128);
        addjob(upd_w2 + (size_t)i * D * D3,    pUpdW2[i], 128, 384);
    }
    k_packall<<<bacc, 256, 0, stream>>>(jobs);

    // ---- edge sort precompute (once per launch) ----
    hipMemsetAsync(cnt, 0, (size_t)N_NODES * 4, stream);
    k_hist<<<(N_EDGES + 255) / 256, 256, 0, stream>>>(edges, cnt);
    k_scan1<<<NCH, 512, 0, stream>>>(cnt, csum);
    k_scan2<<<1, 64, 0, stream>>>(csum, cbase);
    k_scan3<<<NCH, 512, 0, stream>>>(cnt, cbase, rowptr);
    hipMemsetAsync(cnt, 0, (size_t)N_NODES * 4, stream);  // reuse as cursor
    k_scatter<<<(N_EDGES + 255) / 256, 256, 0, stream>>>(edges, r_ij, rhat, rowptr, cnt,
                                                         esrc, ept);

    // ---- state init ----
    hipMemsetAsync(bufV0, 0, (size_t)N_NODES * D3 * 2, stream);
    hipMemsetAsync(d_out, 0, (size_t)out_size * sizeof(float), stream);
    k_embed<<<(N_NODES * D) / 256, 256, 0, stream>>>(z, emb, s);

    const int gN  = gemm_grid(N_NODES);
    const int gN3 = gemm_grid(N_NODES * 3);

    for (int i = 0; i < 3; ++i) {
        short* vstate = (i & 1) ? bufV1 : bufV0;   // current v (bf16)
        short* vscr   = (i & 1) ? bufV0 : bufV1;   // next v
        // h = silu(s @ msg_w1 + b1)
        k_gemm<128, 128, true, 1><<<gN, 256, 0, stream>>>(
            s, nullptr, pMsgW1[i], msg_b1 + (size_t)i * D, hbuf, N_NODES);
        // s_pass = h @ msg_w2 + b2
        k_gemm<128, 384, false, 0><<<gN, 256, 0, stream>>>(
            hbuf, nullptr, pMsgW2[i], msg_b2 + (size_t)i * D3, shrd, N_NODES);
        // segment-sum edge gather: s += ds ; vscr = vstate + dv
        k_edge2<<<4096, 128, 0, stream>>>(rowptr, esrc, ept,
                                          rbf_w + (size_t)i * N_RBF * D3,
                                          rbf_b + (size_t)i * D3,
                                          shrd, vstate, s, vscr);
        // Uv = v @ U (into dead vstate buffer) ; Vv = v @ V
        k_gemm<128, 128, false, 0><<<gN3, 256, 0, stream>>>(
            vscr, nullptr, pU[i], nullptr, vstate, N_NODES * 3);
        k_gemm<128, 128, false, 0><<<gN3, 256, 0, stream>>>(
            vscr, nullptr, pV[i], nullptr, Vv, N_NODES * 3);
        // V_norm (into shrd; s_pass dead now)
        k_svbuild<<<(N_NODES * D) / 256, 256, 0, stream>>>(Vv, Vn);
        // h2 = silu([Vn | s] @ upd_w1 + b1)
        k_gemm<256, 128, true, 2><<<gN, 256, 0, stream>>>(
            Vn, s, pUpdW1[i], upd_b1 + (size_t)i * D, hbuf, N_NODES);
        // a = h2 @ upd_w2 + b2  (clobbers shrd incl. Vn region — Vn already consumed)
        k_gemm<128, 384, false, 0><<<gN, 256, 0, stream>>>(
            hbuf, nullptr, pUpdW2[i], upd_b2 + (size_t)i * D3, shrd, N_NODES);
        // gated update of s and v (in place on vscr)
        k_apply<<<(N_NODES * D) / 256, 256, 0, stream>>>(s, vscr, vstate, Vv, shrd);
    }

    // readout
    k_gemm<128, 128, true, 1><<<gN, 256, 0, stream>>>(
        s, nullptr, pBlue, blue_b1, hbuf, N_NODES);
    k_blue_dot<<<N_NODES / 2, 256, 0, stream>>>(hbuf, graph_idx, blue_w2, blue_b2, out);
}

// Round 5
// 1130.762 us; speedup vs baseline: 4.9122x; 1.0384x over previous
//
#include <hip/hip_runtime.h>
#include <hip/hip_bf16.h>
#include <math.h>

#define N_NODES 50000
#define N_EDGES 400000
#define N_GRAPHS 2500
#define D 128
#define D3 384
#define N_RBF 20
#define R_CUT 5.0f
#define PI_F 3.14159265358979f
#define NCH 98   // ceil(50000/512)
#define GEB 16   // gate edge batch (one MFMA row-block)

typedef __attribute__((ext_vector_type(8))) short bf16x8;
typedef __attribute__((ext_vector_type(4))) float f32x4;

__device__ __forceinline__ float silu_f(float x) {
    return x / (1.0f + __expf(-x));
}
__device__ __forceinline__ short f2bf(float x) {
    union { float f; unsigned u; } v; v.f = x;
    unsigned r = (v.u + 0x7FFFu + ((v.u >> 16) & 1u)) >> 16;
    return (short)r;
}
__device__ __forceinline__ float bf2f(short x) {
    union { unsigned u; float f; } v; v.u = ((unsigned)(unsigned short)x) << 16;
    return v.f;
}

// ---------------- all weight packs in ONE dispatch ----------------
#define MAXJOBS 19
struct PackJobs {
    const float* W[MAXJOBS];
    short* P[MAXJOBS];
    int K[MAXJOBS];
    int N[MAXJOBS];
    int boff[MAXJOBS + 1];
    int njobs;
};
__global__ void k_packall(PackJobs jobs) {
    int b = blockIdx.x;
    int j = 0;
    while (j + 1 < jobs.njobs && b >= jobs.boff[j + 1]) ++j;
    int t = (b - jobs.boff[j]) * 256 + threadIdx.x;
    int K = jobs.K[j], N = jobs.N[j];
    int NKT = K / 32;
    int total = (N / 16) * NKT * 64;
    if (t >= total) return;
    const float* W = jobs.W[j];
    short* P = jobs.P[j];
    int lane = t & 63;
    int kt = (t >> 6) % NKT;
    int nt = (t >> 6) / NKT;
    int k0 = kt * 32 + (lane >> 4) * 8;
    int col = nt * 16 + (lane & 15);
    #pragma unroll
    for (int q = 0; q < 8; ++q)
        P[(size_t)t * 8 + q] = f2bf(W[(size_t)(k0 + q) * N + col]);
}

// pack [rbf_w(20 rows); rbf_b(1 row); zeros] -> frags, 3 blocks in one dispatch
__global__ void k_packrbf(const float* __restrict__ rbf_w, const float* __restrict__ rbf_b,
                          short* __restrict__ P) {
    int t = blockIdx.x * 256 + threadIdx.x;
    if (t >= 3 * 1536) return;
    int i = t / 1536;
    int r = t - i * 1536;        // nt*64 + lane
    int lane = r & 63;
    int nt = r >> 6;
    int col = nt * 16 + (lane & 15);
    int k0 = (lane >> 4) * 8;
    const float* W = rbf_w + (size_t)i * N_RBF * D3;
    const float* B = rbf_b + (size_t)i * D3;
    short* out = P + (size_t)i * 12288 + (size_t)r * 8;
    #pragma unroll
    for (int q = 0; q < 8; ++q) {
        int k = k0 + q;
        float v = (k < N_RBF) ? W[(size_t)k * D3 + col] : ((k == N_RBF) ? B[col] : 0.0f);
        out[q] = f2bf(v);
    }
}

// ---------------- generic MFMA GEMM ----------------
// AMODE: 0 = A bf16 ; 1 = A f32 ; 2 = split A1 bf16 (k<128) + A2 f32 (k>=128)
template<int K, int N, bool SILU, int AMODE>
__global__ __launch_bounds__(256) void k_gemm(const void* __restrict__ Aptr,
                                              const void* __restrict__ A2ptr,
                                              const short* __restrict__ Bp,
                                              const float* __restrict__ bias,
                                              short* __restrict__ Cbf, int M) {
    constexpr int NKT = K / 32, NNT = N / 16;
    int lane = threadIdx.x & 63, wv = threadIdx.x >> 6;
    int tile = blockIdx.x * 4 + wv;
    if (tile * 16 >= M) return;
    int arow = tile * 16 + (lane & 15);
    int kgrp = (lane >> 4) * 8;

    bf16x8 a[NKT];
    if (AMODE == 0) {
        const short* A = (const short*)Aptr + (size_t)arow * K + kgrp;
        #pragma unroll
        for (int kt = 0; kt < NKT; ++kt) a[kt] = *(const bf16x8*)(A + kt * 32);
    } else if (AMODE == 1) {
        const float* A = (const float*)Aptr + (size_t)arow * K + kgrp;
        #pragma unroll
        for (int kt = 0; kt < NKT; ++kt)
            #pragma unroll
            for (int j = 0; j < 8; ++j) a[kt][j] = f2bf(A[kt * 32 + j]);
    } else {
        const short* A1 = (const short*)Aptr + (size_t)arow * 128 + kgrp;
        const float* A2 = (const float*)A2ptr + (size_t)arow * 128 + kgrp;
        #pragma unroll
        for (int kt = 0; kt < 4 && kt < NKT; ++kt) a[kt] = *(const bf16x8*)(A1 + kt * 32);
        #pragma unroll
        for (int kt = 4; kt < NKT; ++kt)
            #pragma unroll
            for (int j = 0; j < 8; ++j) a[kt][j] = f2bf(A2[(kt - 4) * 32 + j]);
    }

    int crow0 = tile * 16 + (lane >> 4) * 4;
    int ccol = lane & 15;
    const bf16x8* Bv = (const bf16x8*)Bp;
    #pragma unroll
    for (int nt = 0; nt < NNT; ++nt) {
        f32x4 acc = {0.f, 0.f, 0.f, 0.f};
        #pragma unroll
        for (int kt = 0; kt < NKT; ++kt) {
            bf16x8 b = Bv[(nt * NKT + kt) * 64 + lane];
            acc = __builtin_amdgcn_mfma_f32_16x16x32_bf16(a[kt], b, acc, 0, 0, 0);
        }
        int col = nt * 16 + ccol;
        float bs = bias ? bias[col] : 0.0f;
        #pragma unroll
        for (int j = 0; j < 4; ++j) {
            float v = acc[j] + bs;
            if (SILU) v = silu_f(v);
            Cbf[(size_t)(crow0 + j) * N + col] = f2bf(v);
        }
    }
}

// ---------------- embed ----------------
__global__ void k_embed(const int* __restrict__ z, const float* __restrict__ emb,
                        float* __restrict__ s) {
    int i = blockIdx.x * blockDim.x + threadIdx.x;
    if (i < N_NODES * D) {
        int n = i >> 7, c = i & 127;
        s[i] = emb[z[n] * D + c];
    }
}

// ---------------- edge-sort precompute ----------------
__global__ void k_hist(const int* __restrict__ edges, int* __restrict__ cnt) {
    int e = blockIdx.x * 256 + threadIdx.x;
    if (e < N_EDGES) atomicAdd(&cnt[edges[2 * e]], 1);
}

__global__ void k_scan1(const int* __restrict__ cnt, int* __restrict__ csum) {
    int t = threadIdx.x;                  // 512 threads
    int g = blockIdx.x * 512 + t;
    int v = (g < N_NODES) ? cnt[g] : 0;
    #pragma unroll
    for (int off = 32; off > 0; off >>= 1) v += __shfl_down(v, off, 64);
    __shared__ int ws[8];
    if ((t & 63) == 0) ws[t >> 6] = v;
    __syncthreads();
    if (t == 0) {
        int sum = 0;
        #pragma unroll
        for (int i = 0; i < 8; ++i) sum += ws[i];
        csum[blockIdx.x] = sum;
    }
}

__global__ void k_scan2(const int* __restrict__ csum, int* __restrict__ cbase) {
    if (threadIdx.x == 0 && blockIdx.x == 0) {
        int s = 0;
        for (int i = 0; i < NCH; ++i) { cbase[i] = s; s += csum[i]; }
    }
}

__global__ void k_scan3(const int* __restrict__ cnt, const int* __restrict__ cbase,
                        int* __restrict__ rowptr) {
    __shared__ int buf[512];
    int t = threadIdx.x;
    int g = blockIdx.x * 512 + t;
    int orig = (g < N_NODES) ? cnt[g] : 0;
    buf[t] = orig;
    __syncthreads();
    for (int off = 1; off < 512; off <<= 1) {
        int v = (t >= off) ? buf[t - off] : 0;
        __syncthreads();
        buf[t] += v;
        __syncthreads();
    }
    if (g < N_NODES) rowptr[g] = cbase[blockIdx.x] + buf[t] - orig;
    if (g == 0 && blockIdx.x == 0) rowptr[N_NODES] = N_EDGES;
}

// scatter edges into dst-sorted order; per edge: erbf[32] bf16 (rbf*fc, fc, 0...), rhat float4
__global__ void k_scatter(const int* __restrict__ edges, const float* __restrict__ r_ij,
                          const float* __restrict__ rhat, const int* __restrict__ rowptr,
                          int* __restrict__ cursor, int* __restrict__ esrc,
                          short* __restrict__ erbf, float4* __restrict__ erhat) {
    int e = blockIdx.x * 256 + threadIdx.x;
    if (e >= N_EDGES) return;
    int dst = edges[2 * e], src = edges[2 * e + 1];
    int p = rowptr[dst] + atomicAdd(&cursor[dst], 1);
    esrc[p] = src;
    float r = r_ij[e];
    float fc = (r <= R_CUT) ? 0.5f * (cosf(PI_F * r / R_CUT) + 1.0f) : 0.0f;
    float inv_r = 1.0f / r;
    short rec[32];
    #pragma unroll
    for (int k = 0; k < N_RBF; ++k)
        rec[k] = f2bf(sinf((float)(k + 1) * (PI_F / R_CUT) * r) * inv_r * fc);
    rec[20] = f2bf(fc);
    #pragma unroll
    for (int k = 21; k < 32; ++k) rec[k] = 0;
    short* out = erbf + (size_t)p * 32;
    #pragma unroll
    for (int k = 0; k < 32; ++k) out[k] = rec[k];
    float4 rh;
    rh.x = rhat[3 * e]; rh.y = rhat[3 * e + 1]; rh.z = rhat[3 * e + 2]; rh.w = 0.f;
    erhat[p] = rh;
}

// ---------------- edge kernel: MFMA gates + gather, one node per 128-thread block ----------------
__global__ __launch_bounds__(128, 4) void k_edge3(
    const int* __restrict__ rowptr, const int* __restrict__ esrc,
    const short* __restrict__ erbf, const float4* __restrict__ erhat,
    const short* __restrict__ pRbf,
    const short* __restrict__ spass, const short* __restrict__ vold,
    float* __restrict__ s, short* __restrict__ vnew) {
    __shared__ short gate_lds[GEB][D3];   // 16 x 384 bf16 = 12 KB
    int tid = threadIdx.x;
    int lane = tid & 63;
    int wv = tid >> 6;         // 0 or 1
    int c = tid;               // channel 0..127
    int ntb = wv * 12;         // this wave's n-tile range
    for (int n = blockIdx.x; n < N_NODES; n += gridDim.x) {
        int p0 = rowptr[n], p1 = rowptr[n + 1];
        float sa = 0.f, va0 = 0.f, va1 = 0.f, va2 = 0.f;
        for (int pb = p0; pb < p1; pb += GEB) {
            // --- MFMA: gates[e][col] for edges [pb, pb+16) (garbage rows unused) ---
            int erow = pb + (lane & 15);
            if (erow >= p1) erow = p1 - 1;
            bf16x8 afrag = *(const bf16x8*)(erbf + (size_t)erow * 32 + (lane >> 4) * 8);
            int r0 = (lane >> 4) * 4;
            int fcol = lane & 15;
            #pragma unroll
            for (int t = 0; t < 12; ++t) {
                int nt = ntb + t;
                bf16x8 b = *(const bf16x8*)(pRbf + ((size_t)(nt * 64 + lane)) * 8);
                f32x4 acc = {0.f, 0.f, 0.f, 0.f};
                acc = __builtin_amdgcn_mfma_f32_16x16x32_bf16(afrag, b, acc, 0, 0, 0);
                int col = nt * 16 + fcol;
                #pragma unroll
                for (int j = 0; j < 4; ++j)
                    gate_lds[r0 + j][col] = f2bf(acc[j]);
            }
            __syncthreads();
            // --- gather-accumulate over this batch ---
            int pe = (pb + GEB < p1) ? pb + GEB : p1;
            for (int p = pb; p < pe; ++p) {
                int src = esrc[p];
                float4 rh = erhat[p];
                const short* g = gate_lds[p - pb];
                float a0 = bf2f(g[c]);
                float a1 = bf2f(g[128 + c]);
                float a2 = bf2f(g[256 + c]);
                const short* sp = spass + (size_t)src * D3;
                float dv = a0 * bf2f(sp[c]);
                float ds = a1 * bf2f(sp[128 + c]);
                float dr = a2 * bf2f(sp[256 + c]);
                sa += ds;
                const short* vs = vold + (size_t)src * D3;
                va0 += bf2f(vs[c]) * dv + rh.x * dr;
                va1 += bf2f(vs[128 + c]) * dv + rh.y * dr;
                va2 += bf2f(vs[256 + c]) * dv + rh.z * dr;
            }
            __syncthreads();
        }
        s[(size_t)n * D + c] += sa;
        size_t vb = (size_t)n * D3;
        vnew[vb + c]       = f2bf(bf2f(vold[vb + c]) + va0);
        vnew[vb + 128 + c] = f2bf(bf2f(vold[vb + 128 + c]) + va1);
        vnew[vb + 256 + c] = f2bf(bf2f(vold[vb + 256 + c]) + va2);
    }
}

// ---------------- V_norm ----------------
__global__ void k_svbuild(const short* __restrict__ Vv, short* __restrict__ Vn) {
    int i = blockIdx.x * 256 + threadIdx.x;   // over N_NODES*D
    int n = i >> 7, c = i & 127;
    float acc = 0.f;
    #pragma unroll
    for (int d = 0; d < 3; ++d) {
        float v = bf2f(Vv[(size_t)(n * 3 + d) * D + c]);
        acc += v * v;
    }
    Vn[i] = f2bf(sqrtf(acc));
}

// ---------------- apply gated update (v state in place, bf16) ----------------
__global__ void k_apply(float* __restrict__ s, short* __restrict__ v,
                        const short* __restrict__ Uv, const short* __restrict__ Vv,
                        const short* __restrict__ a_bf) {
    int i = blockIdx.x * 256 + threadIdx.x;   // over N_NODES*D
    int n = i >> 7, c = i & 127;
    float avv = bf2f(a_bf[(size_t)n * D3 + c]);
    float asv = bf2f(a_bf[(size_t)n * D3 + 128 + c]);
    float ass = bf2f(a_bf[(size_t)n * D3 + 256 + c]);
    float scal = 0.f;
    float uvr[3];
    #pragma unroll
    for (int d = 0; d < 3; ++d) {
        float u = bf2f(Uv[(size_t)(n * 3 + d) * D + c]);
        float vv = bf2f(Vv[(size_t)(n * 3 + d) * D + c]);
        uvr[d] = u;
        scal += u * vv;
    }
    s[i] += scal * asv + ass;
    #pragma unroll
    for (int d = 0; d < 3; ++d) {
        size_t idx = (size_t)n * D3 + d * 128 + c;
        v[idx] = f2bf(bf2f(v[idx]) + avv * uvr[d]);
    }
}

// ---------------- readout ----------------
__global__ void k_blue_dot(const short* __restrict__ h, const int* __restrict__ graph_idx,
                           const float* __restrict__ w2, const float* __restrict__ b2,
                           float* __restrict__ out) {
    __shared__ float red[4];
    int c = threadIdx.x & 127;
    int n = blockIdx.x * 2 + (threadIdx.x >> 7);
    float val = bf2f(h[(size_t)n * D + c]) * w2[c];
    #pragma unroll
    for (int off = 32; off > 0; off >>= 1) val += __shfl_down(val, off, 64);
    if ((threadIdx.x & 63) == 0) red[threadIdx.x >> 6] = val;
    __syncthreads();
    if (threadIdx.x == 0)   atomicAdd(&out[graph_idx[n]], red[0] + red[1] + b2[0]);
    if (threadIdx.x == 128) atomicAdd(&out[graph_idx[n]], red[2] + red[3] + b2[0]);
}

static inline int gemm_grid(int M) { return (M / 16 + 3) / 4; }

extern "C" void kernel_launch(void* const* d_in, const int* in_sizes, int n_in,
                              void* d_out, int out_size, void* d_ws, size_t ws_size,
                              hipStream_t stream) {
    const int*   z         = (const int*)d_in[0];
    const int*   edges     = (const int*)d_in[1];
    const float* r_ij      = (const float*)d_in[2];
    const float* rhat      = (const float*)d_in[3];
    const int*   graph_idx = (const int*)d_in[4];
    const float* emb       = (const float*)d_in[5];
    const float* msg_w1    = (const float*)d_in[6];
    const float* msg_b1    = (const float*)d_in[7];
    const float* msg_w2    = (const float*)d_in[8];
    const float* msg_b2    = (const float*)d_in[9];
    const float* rbf_w     = (const float*)d_in[10];
    const float* rbf_b     = (const float*)d_in[11];
    const float* upd_U     = (const float*)d_in[12];
    const float* upd_V     = (const float*)d_in[13];
    const float* upd_w1    = (const float*)d_in[14];
    const float* upd_b1    = (const float*)d_in[15];
    const float* upd_w2    = (const float*)d_in[16];
    const float* upd_b2    = (const float*)d_in[17];
    const float* blue_w1   = (const float*)d_in[18];
    const float* blue_b1   = (const float*)d_in[19];
    const float* blue_w2   = (const float*)d_in[20];
    const float* blue_b2   = (const float*)d_in[21];
    float* out = (float*)d_out;

    char* ws = (char*)d_ws;
    size_t off = 0;
    auto alloc = [&](size_t bytes) { void* p = ws + off; off += (bytes + 255) & ~(size_t)255; return p; };

    float* s      = (float*)alloc((size_t)N_NODES * D * 4);            // 25.6 MB
    short* bufV0  = (short*)alloc((size_t)N_NODES * D3 * 2);           // 38.4 MB
    short* bufV1  = (short*)alloc((size_t)N_NODES * D3 * 2);           // 38.4 MB
    short* shrd   = (short*)alloc((size_t)N_NODES * D3 * 2);           // 38.4 MB: s_pass -> Vn -> a
    short* hbuf   = (short*)alloc((size_t)N_NODES * D * 2);            // 12.8 MB
    short* Vv     = (short*)alloc((size_t)N_NODES * D3 * 2);           // 38.4 MB
    short* Vn     = shrd;   // aliases shrd
    // edge tables
    int*    esrc   = (int*)alloc((size_t)N_EDGES * 4);                 // 1.6 MB
    short*  erbf   = (short*)alloc((size_t)N_EDGES * 32 * 2);          // 25.6 MB
    float4* erhat  = (float4*)alloc((size_t)N_EDGES * 16);             // 6.4 MB
    int*    rowptr = (int*)alloc((size_t)(N_NODES + 1) * 4);
    int*    cnt    = (int*)alloc((size_t)N_NODES * 4);                 // hist then cursor
    int*    csum   = (int*)alloc(NCH * 4);
    int*    cbase  = (int*)alloc(NCH * 4);

    // packed weights
    short* pBlue = (short*)alloc(16384 * 2);
    short* pRbfAll = (short*)alloc((size_t)3 * 12288 * 2);             // rbf gate frags
    short* pMsgW1[3]; short* pMsgW2[3]; short* pU[3]; short* pV[3]; short* pUpdW1[3]; short* pUpdW2[3];
    for (int i = 0; i < 3; ++i) {
        pMsgW1[i] = (short*)alloc(16384 * 2);
        pMsgW2[i] = (short*)alloc(49152 * 2);
        pU[i]     = (short*)alloc(16384 * 2);
        pV[i]     = (short*)alloc(16384 * 2);
        pUpdW1[i] = (short*)alloc(32768 * 2);
        pUpdW2[i] = (short*)alloc(49152 * 2);
    }

    // ---- all GEMM-weight packs in one dispatch ----
    PackJobs jobs;
    jobs.njobs = 0;
    int bacc = 0;
    auto addjob = [&](const float* W, short* P, int K, int N) {
        int j = jobs.njobs++;
        jobs.W[j] = W; jobs.P[j] = P; jobs.K[j] = K; jobs.N[j] = N;
        jobs.boff[j] = bacc;
        int total = (N / 16) * (K / 32) * 64;
        bacc += (total + 255) / 256;
        jobs.boff[j + 1] = bacc;
    };
    addjob(blue_w1, pBlue, 128, 128);
    for (int i = 0; i < 3; ++i) {
        addjob(msg_w1 + (size_t)i * D * D,     pMsgW1[i], 128, 128);
        addjob(msg_w2 + (size_t)i * D * D3,    pMsgW2[i], 128, 384);
        addjob(upd_U  + (size_t)i * D * D,     pU[i],     128, 128);
        addjob(upd_V  + (size_t)i * D * D,     pV[i],     128, 128);
        addjob(upd_w1 + (size_t)i * 2 * D * D, pUpdW1[i], 256, 128);
        addjob(upd_w2 + (size_t)i * D * D3,    pUpdW2[i], 128, 384);
    }
    k_packall<<<bacc, 256, 0, stream>>>(jobs);
    k_packrbf<<<18, 256, 0, stream>>>(rbf_w, rbf_b, pRbfAll);

    // ---- edge sort precompute (once per launch) ----
    hipMemsetAsync(cnt, 0, (size_t)N_NODES * 4, stream);
    k_hist<<<(N_EDGES + 255) / 256, 256, 0, stream>>>(edges, cnt);
    k_scan1<<<NCH, 512, 0, stream>>>(cnt, csum);
    k_scan2<<<1, 64, 0, stream>>>(csum, cbase);
    k_scan3<<<NCH, 512, 0, stream>>>(cnt, cbase, rowptr);
    hipMemsetAsync(cnt, 0, (size_t)N_NODES * 4, stream);  // reuse as cursor
    k_scatter<<<(N_EDGES + 255) / 256, 256, 0, stream>>>(edges, r_ij, rhat, rowptr, cnt,
                                                         esrc, erbf, erhat);

    // ---- state init ----
    hipMemsetAsync(bufV0, 0, (size_t)N_NODES * D3 * 2, stream);
    hipMemsetAsync(d_out, 0, (size_t)out_size * sizeof(float), stream);
    k_embed<<<(N_NODES * D) / 256, 256, 0, stream>>>(z, emb, s);

    const int gN  = gemm_grid(N_NODES);
    const int gN3 = gemm_grid(N_NODES * 3);

    for (int i = 0; i < 3; ++i) {
        short* vstate = (i & 1) ? bufV1 : bufV0;   // current v (bf16)
        short* vscr   = (i & 1) ? bufV0 : bufV1;   // next v
        // h = silu(s @ msg_w1 + b1)
        k_gemm<128, 128, true, 1><<<gN, 256, 0, stream>>>(
            s, nullptr, pMsgW1[i], msg_b1 + (size_t)i * D, hbuf, N_NODES);
        // s_pass = h @ msg_w2 + b2
        k_gemm<128, 384, false, 0><<<gN, 256, 0, stream>>>(
            hbuf, nullptr, pMsgW2[i], msg_b2 + (size_t)i * D3, shrd, N_NODES);
        // segment-sum edge gather with MFMA gates: s += ds ; vscr = vstate + dv
        k_edge3<<<2048, 128, 0, stream>>>(rowptr, esrc, erbf, erhat,
                                          pRbfAll + (size_t)i * 12288,
                                          shrd, vstate, s, vscr);
        // Uv = v @ U (into dead vstate buffer) ; Vv = v @ V
        k_gemm<128, 128, false, 0><<<gN3, 256, 0, stream>>>(
            vscr, nullptr, pU[i], nullptr, vstate, N_NODES * 3);
        k_gemm<128, 128, false, 0><<<gN3, 256, 0, stream>>>(
            vscr, nullptr, pV[i], nullptr, Vv, N_NODES * 3);
        // V_norm (into shrd; s_pass dead now)
        k_svbuild<<<(N_NODES * D) / 256, 256, 0, stream>>>(Vv, Vn);
        // h2 = silu([Vn | s] @ upd_w1 + b1)
        k_gemm<256, 128, true, 2><<<gN, 256, 0, stream>>>(
            Vn, s, pUpdW1[i], upd_b1 + (size_t)i * D, hbuf, N_NODES);
        // a = h2 @ upd_w2 + b2  (clobbers shrd incl. Vn region — Vn already consumed)
        k_gemm<128, 384, false, 0><<<gN, 256, 0, stream>>>(
            hbuf, nullptr, pUpdW2[i], upd_b2 + (size_t)i * D3, shrd, N_NODES);
        // gated update of s and v (in place on vscr)
        k_apply<<<(N_NODES * D) / 256, 256, 0, stream>>>(s, vscr, vstate, Vv, shrd);
    }

    // readout
    k_gemm<128, 128, true, 1><<<gN, 256, 0, stream>>>(
        s, nullptr, pBlue, blue_b1, hbuf, N_NODES);
    k_blue_dot<<<N_NODES / 2, 256, 0, stream>>>(hbuf, graph_idx, blue_w2, blue_b2, out);
}

// Round 6
// 1020.716 us; speedup vs baseline: 5.4417x; 1.1078x over previous
//
#include <hip/hip_runtime.h>
#include <hip/hip_bf16.h>
#include <math.h>

#define N_NODES 50000
#define N_EDGES 400000
#define N_GRAPHS 2500
#define D 128
#define D3 384
#define N_RBF 20
#define R_CUT 5.0f
#define PI_F 3.14159265358979f
#define NCH 98   // ceil(50000/512)
#define GEB 16   // gate edge batch (one MFMA row-block)
#define GLDS_STRIDE 388  // pad: 776 B row stride -> disjoint bank windows

typedef __attribute__((ext_vector_type(8))) short bf16x8;
typedef __attribute__((ext_vector_type(4))) float f32x4;

__device__ __forceinline__ float silu_f(float x) {
    return x / (1.0f + __expf(-x));
}
__device__ __forceinline__ short f2bf(float x) {
    union { float f; unsigned u; } v; v.f = x;
    unsigned r = (v.u + 0x7FFFu + ((v.u >> 16) & 1u)) >> 16;
    return (short)r;
}
__device__ __forceinline__ float bf2f(short x) {
    union { unsigned u; float f; } v; v.u = ((unsigned)(unsigned short)x) << 16;
    return v.f;
}

// ---------------- all weight packs in ONE dispatch ----------------
#define MAXJOBS 19
struct PackJobs {
    const float* W[MAXJOBS];
    short* P[MAXJOBS];
    int K[MAXJOBS];
    int N[MAXJOBS];
    int boff[MAXJOBS + 1];
    int njobs;
};
__global__ void k_packall(PackJobs jobs) {
    int b = blockIdx.x;
    int j = 0;
    while (j + 1 < jobs.njobs && b >= jobs.boff[j + 1]) ++j;
    int t = (b - jobs.boff[j]) * 256 + threadIdx.x;
    int K = jobs.K[j], N = jobs.N[j];
    int NKT = K / 32;
    int total = (N / 16) * NKT * 64;
    if (t >= total) return;
    const float* W = jobs.W[j];
    short* P = jobs.P[j];
    int lane = t & 63;
    int kt = (t >> 6) % NKT;
    int nt = (t >> 6) / NKT;
    int k0 = kt * 32 + (lane >> 4) * 8;
    int col = nt * 16 + (lane & 15);
    #pragma unroll
    for (int q = 0; q < 8; ++q)
        P[(size_t)t * 8 + q] = f2bf(W[(size_t)(k0 + q) * N + col]);
}

// pack [rbf_w(20 rows); rbf_b(1 row); zeros] -> frags, 3 blocks in one dispatch
__global__ void k_packrbf(const float* __restrict__ rbf_w, const float* __restrict__ rbf_b,
                          short* __restrict__ P) {
    int t = blockIdx.x * 256 + threadIdx.x;
    if (t >= 3 * 1536) return;
    int i = t / 1536;
    int r = t - i * 1536;        // nt*64 + lane
    int lane = r & 63;
    int nt = r >> 6;
    int col = nt * 16 + (lane & 15);
    int k0 = (lane >> 4) * 8;
    const float* W = rbf_w + (size_t)i * N_RBF * D3;
    const float* B = rbf_b + (size_t)i * D3;
    short* out = P + (size_t)i * 12288 + (size_t)r * 8;
    #pragma unroll
    for (int q = 0; q < 8; ++q) {
        int k = k0 + q;
        float v = (k < N_RBF) ? W[(size_t)k * D3 + col] : ((k == N_RBF) ? B[col] : 0.0f);
        out[q] = f2bf(v);
    }
}

// ---------------- generic MFMA GEMM ----------------
// AMODE: 0 = A bf16 ; 1 = A f32 ; 2 = split A1 bf16 (k<128) + A2 f32 (k>=128)
template<int K, int N, bool SILU, int AMODE>
__global__ __launch_bounds__(256) void k_gemm(const void* __restrict__ Aptr,
                                              const void* __restrict__ A2ptr,
                                              const short* __restrict__ Bp,
                                              const float* __restrict__ bias,
                                              short* __restrict__ Cbf, int M) {
    constexpr int NKT = K / 32, NNT = N / 16;
    int lane = threadIdx.x & 63, wv = threadIdx.x >> 6;
    int tile = blockIdx.x * 4 + wv;
    if (tile * 16 >= M) return;
    int arow = tile * 16 + (lane & 15);
    int kgrp = (lane >> 4) * 8;

    bf16x8 a[NKT];
    if (AMODE == 0) {
        const short* A = (const short*)Aptr + (size_t)arow * K + kgrp;
        #pragma unroll
        for (int kt = 0; kt < NKT; ++kt) a[kt] = *(const bf16x8*)(A + kt * 32);
    } else if (AMODE == 1) {
        const float* A = (const float*)Aptr + (size_t)arow * K + kgrp;
        #pragma unroll
        for (int kt = 0; kt < NKT; ++kt)
            #pragma unroll
            for (int j = 0; j < 8; ++j) a[kt][j] = f2bf(A[kt * 32 + j]);
    } else {
        const short* A1 = (const short*)Aptr + (size_t)arow * 128 + kgrp;
        const float* A2 = (const float*)A2ptr + (size_t)arow * 128 + kgrp;
        #pragma unroll
        for (int kt = 0; kt < 4 && kt < NKT; ++kt) a[kt] = *(const bf16x8*)(A1 + kt * 32);
        #pragma unroll
        for (int kt = 4; kt < NKT; ++kt)
            #pragma unroll
            for (int j = 0; j < 8; ++j) a[kt][j] = f2bf(A2[(kt - 4) * 32 + j]);
    }

    int crow0 = tile * 16 + (lane >> 4) * 4;
    int ccol = lane & 15;
    const bf16x8* Bv = (const bf16x8*)Bp;
    #pragma unroll
    for (int nt = 0; nt < NNT; ++nt) {
        f32x4 acc = {0.f, 0.f, 0.f, 0.f};
        #pragma unroll
        for (int kt = 0; kt < NKT; ++kt) {
            bf16x8 b = Bv[(nt * NKT + kt) * 64 + lane];
            acc = __builtin_amdgcn_mfma_f32_16x16x32_bf16(a[kt], b, acc, 0, 0, 0);
        }
        int col = nt * 16 + ccol;
        float bs = bias ? bias[col] : 0.0f;
        #pragma unroll
        for (int j = 0; j < 4; ++j) {
            float v = acc[j] + bs;
            if (SILU) v = silu_f(v);
            Cbf[(size_t)(crow0 + j) * N + col] = f2bf(v);
        }
    }
}

// ---------------- fused U/V GEMM: one A read, two C outputs ----------------
__global__ __launch_bounds__(256) void k_gemmUV(const short* __restrict__ A,
                                                const short* __restrict__ Bp,
                                                short* __restrict__ Cu,
                                                short* __restrict__ Cv, int M) {
    int lane = threadIdx.x & 63, wv = threadIdx.x >> 6;
    int tile = blockIdx.x * 4 + wv;
    if (tile * 16 >= M) return;
    int arow = tile * 16 + (lane & 15);
    int kgrp = (lane >> 4) * 8;
    const short* Ar = A + (size_t)arow * 128 + kgrp;
    bf16x8 a[4];
    #pragma unroll
    for (int kt = 0; kt < 4; ++kt) a[kt] = *(const bf16x8*)(Ar + kt * 32);
    int crow0 = tile * 16 + (lane >> 4) * 4;
    int ccol = lane & 15;
    const bf16x8* Bv = (const bf16x8*)Bp;
    #pragma unroll
    for (int nt = 0; nt < 16; ++nt) {
        f32x4 acc = {0.f, 0.f, 0.f, 0.f};
        #pragma unroll
        for (int kt = 0; kt < 4; ++kt)
            acc = __builtin_amdgcn_mfma_f32_16x16x32_bf16(a[kt], Bv[(nt * 4 + kt) * 64 + lane], acc, 0, 0, 0);
        int col = nt * 16 + ccol;
        short* C = (col < 128) ? Cu : Cv;
        int cc = col & 127;
        #pragma unroll
        for (int j = 0; j < 4; ++j)
            C[(size_t)(crow0 + j) * 128 + cc] = f2bf(acc[j]);
    }
}

// ---------------- embed ----------------
__global__ void k_embed(const int* __restrict__ z, const float* __restrict__ emb,
                        float* __restrict__ s) {
    int i = blockIdx.x * blockDim.x + threadIdx.x;
    if (i < N_NODES * D) {
        int n = i >> 7, c = i & 127;
        s[i] = emb[z[n] * D + c];
    }
}

// ---------------- edge-sort precompute ----------------
__global__ void k_hist(const int* __restrict__ edges, int* __restrict__ cnt) {
    int e = blockIdx.x * 256 + threadIdx.x;
    if (e < N_EDGES) atomicAdd(&cnt[edges[2 * e]], 1);
}

__global__ void k_scan1(const int* __restrict__ cnt, int* __restrict__ csum) {
    int t = threadIdx.x;                  // 512 threads
    int g = blockIdx.x * 512 + t;
    int v = (g < N_NODES) ? cnt[g] : 0;
    #pragma unroll
    for (int off = 32; off > 0; off >>= 1) v += __shfl_down(v, off, 64);
    __shared__ int ws[8];
    if ((t & 63) == 0) ws[t >> 6] = v;
    __syncthreads();
    if (t == 0) {
        int sum = 0;
        #pragma unroll
        for (int i = 0; i < 8; ++i) sum += ws[i];
        csum[blockIdx.x] = sum;
    }
}

__global__ void k_scan2(const int* __restrict__ csum, int* __restrict__ cbase) {
    if (threadIdx.x == 0 && blockIdx.x == 0) {
        int s = 0;
        for (int i = 0; i < NCH; ++i) { cbase[i] = s; s += csum[i]; }
    }
}

__global__ void k_scan3(const int* __restrict__ cnt, const int* __restrict__ cbase,
                        int* __restrict__ rowptr) {
    __shared__ int buf[512];
    int t = threadIdx.x;
    int g = blockIdx.x * 512 + t;
    int orig = (g < N_NODES) ? cnt[g] : 0;
    buf[t] = orig;
    __syncthreads();
    for (int off = 1; off < 512; off <<= 1) {
        int v = (t >= off) ? buf[t - off] : 0;
        __syncthreads();
        buf[t] += v;
        __syncthreads();
    }
    if (g < N_NODES) rowptr[g] = cbase[blockIdx.x] + buf[t] - orig;
    if (g == 0 && blockIdx.x == 0) rowptr[N_NODES] = N_EDGES;
}

// scatter edges into dst-sorted order; per edge: erbf[32] bf16 (rbf*fc, fc, 0...), rhat float4
__global__ void k_scatter(const int* __restrict__ edges, const float* __restrict__ r_ij,
                          const float* __restrict__ rhat, const int* __restrict__ rowptr,
                          int* __restrict__ cursor, int* __restrict__ esrc,
                          short* __restrict__ erbf, float4* __restrict__ erhat) {
    int e = blockIdx.x * 256 + threadIdx.x;
    if (e >= N_EDGES) return;
    int dst = edges[2 * e], src = edges[2 * e + 1];
    int p = rowptr[dst] + atomicAdd(&cursor[dst], 1);
    esrc[p] = src;
    float r = r_ij[e];
    float fc = (r <= R_CUT) ? 0.5f * (cosf(PI_F * r / R_CUT) + 1.0f) : 0.0f;
    float inv_r = 1.0f / r;
    short rec[32];
    #pragma unroll
    for (int k = 0; k < N_RBF; ++k)
        rec[k] = f2bf(sinf((float)(k + 1) * (PI_F / R_CUT) * r) * inv_r * fc);
    rec[20] = f2bf(fc);
    #pragma unroll
    for (int k = 21; k < 32; ++k) rec[k] = 0;
    short* out = erbf + (size_t)p * 32;
    #pragma unroll
    for (int k = 0; k < 32; ++k) out[k] = rec[k];
    float4 rh;
    rh.x = rhat[3 * e]; rh.y = rhat[3 * e + 1]; rh.z = rhat[3 * e + 2]; rh.w = 0.f;
    erhat[p] = rh;
}

// ---------------- edge kernel: MFMA gates + gather, one node per 128-thread block ----------------
__global__ __launch_bounds__(128, 4) void k_edge3(
    const int* __restrict__ rowptr, const int* __restrict__ esrc,
    const short* __restrict__ erbf, const float4* __restrict__ erhat,
    const short* __restrict__ pRbf,
    const short* __restrict__ spass, const short* __restrict__ vold,
    float* __restrict__ s, short* __restrict__ vnew) {
    __shared__ short gate_lds[GEB * GLDS_STRIDE];  // 16 x 388 bf16, padded stride
    __shared__ int   src_lds[GEB];
    __shared__ float4 rh_lds[GEB];
    int tid = threadIdx.x;
    int lane = tid & 63;
    int wv = tid >> 6;         // 0 or 1
    int c = tid;               // channel 0..127
    int ntb = wv * 12;         // this wave's n-tile range
    // hoist B fragments into registers (loop-invariant, 48 VGPRs)
    bf16x8 bfr[12];
    #pragma unroll
    for (int t = 0; t < 12; ++t)
        bfr[t] = *(const bf16x8*)(pRbf + ((size_t)((ntb + t) * 64 + lane)) * 8);
    int r0 = (lane >> 4) * 4;
    int fcol = lane & 15;
    for (int n = blockIdx.x; n < N_NODES; n += gridDim.x) {
        int p0 = rowptr[n], p1 = rowptr[n + 1];
        float sa = 0.f, va0 = 0.f, va1 = 0.f, va2 = 0.f;
        for (int pb = p0; pb < p1; pb += GEB) {
            // --- MFMA gate phase + stage esrc/erhat into LDS ---
            int erow = pb + (lane & 15);
            if (erow >= p1) erow = p1 - 1;
            bf16x8 afrag = *(const bf16x8*)(erbf + (size_t)erow * 32 + (lane >> 4) * 8);
            if (tid < GEB) {
                int p = pb + tid;
                if (p < p1) { src_lds[tid] = esrc[p]; rh_lds[tid] = erhat[p]; }
            }
            #pragma unroll
            for (int t = 0; t < 12; ++t) {
                f32x4 acc = {0.f, 0.f, 0.f, 0.f};
                acc = __builtin_amdgcn_mfma_f32_16x16x32_bf16(afrag, bfr[t], acc, 0, 0, 0);
                int col = (ntb + t) * 16 + fcol;
                #pragma unroll
                for (int j = 0; j < 4; ++j)
                    gate_lds[(r0 + j) * GLDS_STRIDE + col] = f2bf(acc[j]);
            }
            __syncthreads();
            // --- gather-accumulate over this batch ---
            int pe = (pb + GEB < p1) ? pb + GEB : p1;
            for (int p = pb; p < pe; ++p) {
                int src = src_lds[p - pb];
                float4 rh = rh_lds[p - pb];
                const short* g = gate_lds + (p - pb) * GLDS_STRIDE;
                float a0 = bf2f(g[c]);
                float a1 = bf2f(g[128 + c]);
                float a2 = bf2f(g[256 + c]);
                const short* sp = spass + (size_t)src * D3;
                float dv = a0 * bf2f(sp[c]);
                float ds = a1 * bf2f(sp[128 + c]);
                float dr = a2 * bf2f(sp[256 + c]);
                sa += ds;
                const short* vs = vold + (size_t)src * D3;
                va0 += bf2f(vs[c]) * dv + rh.x * dr;
                va1 += bf2f(vs[128 + c]) * dv + rh.y * dr;
                va2 += bf2f(vs[256 + c]) * dv + rh.z * dr;
            }
            __syncthreads();
        }
        s[(size_t)n * D + c] += sa;
        size_t vb = (size_t)n * D3;
        vnew[vb + c]       = f2bf(bf2f(vold[vb + c]) + va0);
        vnew[vb + 128 + c] = f2bf(bf2f(vold[vb + 128 + c]) + va1);
        vnew[vb + 256 + c] = f2bf(bf2f(vold[vb + 256 + c]) + va2);
    }
}

// ---------------- V_norm ----------------
__global__ void k_svbuild(const short* __restrict__ Vv, short* __restrict__ Vn) {
    int i = blockIdx.x * 256 + threadIdx.x;   // over N_NODES*D
    int n = i >> 7, c = i & 127;
    float acc = 0.f;
    #pragma unroll
    for (int d = 0; d < 3; ++d) {
        float v = bf2f(Vv[(size_t)(n * 3 + d) * D + c]);
        acc += v * v;
    }
    Vn[i] = f2bf(sqrtf(acc));
}

// ---------------- apply gated update (v state in place, bf16) ----------------
__global__ void k_apply(float* __restrict__ s, short* __restrict__ v,
                        const short* __restrict__ Uv, const short* __restrict__ Vv,
                        const short* __restrict__ a_bf) {
    int i = blockIdx.x * 256 + threadIdx.x;   // over N_NODES*D
    int n = i >> 7, c = i & 127;
    float avv = bf2f(a_bf[(size_t)n * D3 + c]);
    float asv = bf2f(a_bf[(size_t)n * D3 + 128 + c]);
    float ass = bf2f(a_bf[(size_t)n * D3 + 256 + c]);
    float scal = 0.f;
    float uvr[3];
    #pragma unroll
    for (int d = 0; d < 3; ++d) {
        float u = bf2f(Uv[(size_t)(n * 3 + d) * D + c]);
        float vv = bf2f(Vv[(size_t)(n * 3 + d) * D + c]);
        uvr[d] = u;
        scal += u * vv;
    }
    s[i] += scal * asv + ass;
    #pragma unroll
    for (int d = 0; d < 3; ++d) {
        size_t idx = (size_t)n * D3 + d * 128 + c;
        v[idx] = f2bf(bf2f(v[idx]) + avv * uvr[d]);
    }
}

// ---------------- readout ----------------
__global__ void k_blue_dot(const short* __restrict__ h, const int* __restrict__ graph_idx,
                           const float* __restrict__ w2, const float* __restrict__ b2,
                           float* __restrict__ out) {
    __shared__ float red[4];
    int c = threadIdx.x & 127;
    int n = blockIdx.x * 2 + (threadIdx.x >> 7);
    float val = bf2f(h[(size_t)n * D + c]) * w2[c];
    #pragma unroll
    for (int off = 32; off > 0; off >>= 1) val += __shfl_down(val, off, 64);
    if ((threadIdx.x & 63) == 0) red[threadIdx.x >> 6] = val;
    __syncthreads();
    if (threadIdx.x == 0)   atomicAdd(&out[graph_idx[n]], red[0] + red[1] + b2[0]);
    if (threadIdx.x == 128) atomicAdd(&out[graph_idx[n]], red[2] + red[3] + b2[0]);
}

static inline int gemm_grid(int M) { return (M / 16 + 3) / 4; }

extern "C" void kernel_launch(void* const* d_in, const int* in_sizes, int n_in,
                              void* d_out, int out_size, void* d_ws, size_t ws_size,
                              hipStream_t stream) {
    const int*   z         = (const int*)d_in[0];
    const int*   edges     = (const int*)d_in[1];
    const float* r_ij      = (const float*)d_in[2];
    const float* rhat      = (const float*)d_in[3];
    const int*   graph_idx = (const int*)d_in[4];
    const float* emb       = (const float*)d_in[5];
    const float* msg_w1    = (const float*)d_in[6];
    const float* msg_b1    = (const float*)d_in[7];
    const float* msg_w2    = (const float*)d_in[8];
    const float* msg_b2    = (const float*)d_in[9];
    const float* rbf_w     = (const float*)d_in[10];
    const float* rbf_b     = (const float*)d_in[11];
    const float* upd_U     = (const float*)d_in[12];
    const float* upd_V     = (const float*)d_in[13];
    const float* upd_w1    = (const float*)d_in[14];
    const float* upd_b1    = (const float*)d_in[15];
    const float* upd_w2    = (const float*)d_in[16];
    const float* upd_b2    = (const float*)d_in[17];
    const float* blue_w1   = (const float*)d_in[18];
    const float* blue_b1   = (const float*)d_in[19];
    const float* blue_w2   = (const float*)d_in[20];
    const float* blue_b2   = (const float*)d_in[21];
    float* out = (float*)d_out;

    char* ws = (char*)d_ws;
    size_t off = 0;
    auto alloc = [&](size_t bytes) { void* p = ws + off; off += (bytes + 255) & ~(size_t)255; return p; };

    float* s      = (float*)alloc((size_t)N_NODES * D * 4);            // 25.6 MB
    short* bufV0  = (short*)alloc((size_t)N_NODES * D3 * 2);           // 38.4 MB
    short* bufV1  = (short*)alloc((size_t)N_NODES * D3 * 2);           // 38.4 MB
    short* shrd   = (short*)alloc((size_t)N_NODES * D3 * 2);           // 38.4 MB: s_pass -> Vn -> a
    short* hbuf   = (short*)alloc((size_t)N_NODES * D * 2);            // 12.8 MB
    short* Vv     = (short*)alloc((size_t)N_NODES * D3 * 2);           // 38.4 MB
    short* Vn     = shrd;   // aliases shrd
    // edge tables
    int*    esrc   = (int*)alloc((size_t)N_EDGES * 4);                 // 1.6 MB
    short*  erbf   = (short*)alloc((size_t)N_EDGES * 32 * 2);          // 25.6 MB
    float4* erhat  = (float4*)alloc((size_t)N_EDGES * 16);             // 6.4 MB
    int*    rowptr = (int*)alloc((size_t)(N_NODES + 1) * 4);
    int*    cnt    = (int*)alloc((size_t)N_NODES * 4);                 // hist then cursor
    int*    csum   = (int*)alloc(NCH * 4);
    int*    cbase  = (int*)alloc(NCH * 4);

    // packed weights
    short* pBlue = (short*)alloc(16384 * 2);
    short* pRbfAll = (short*)alloc((size_t)3 * 12288 * 2);             // rbf gate frags
    short* pMsgW1[3]; short* pMsgW2[3]; short* pUV[3]; short* pUpdW1[3]; short* pUpdW2[3];
    for (int i = 0; i < 3; ++i) {
        pMsgW1[i] = (short*)alloc(16384 * 2);
        pMsgW2[i] = (short*)alloc(49152 * 2);
        pUV[i]    = (short*)alloc(32768 * 2);   // U tiles then V tiles
        pUpdW1[i] = (short*)alloc(32768 * 2);
        pUpdW2[i] = (short*)alloc(49152 * 2);
    }

    // ---- all GEMM-weight packs in one dispatch ----
    PackJobs jobs;
    jobs.njobs = 0;
    int bacc = 0;
    auto addjob = [&](const float* W, short* P, int K, int N) {
        int j = jobs.njobs++;
        jobs.W[j] = W; jobs.P[j] = P; jobs.K[j] = K; jobs.N[j] = N;
        jobs.boff[j] = bacc;
        int total = (N / 16) * (K / 32) * 64;
        bacc += (total + 255) / 256;
        jobs.boff[j + 1] = bacc;
    };
    addjob(blue_w1, pBlue, 128, 128);
    for (int i = 0; i < 3; ++i) {
        addjob(msg_w1 + (size_t)i * D * D,     pMsgW1[i], 128, 128);
        addjob(msg_w2 + (size_t)i * D * D3,    pMsgW2[i], 128, 384);
        addjob(upd_U  + (size_t)i * D * D,     pUV[i],          128, 128);
        addjob(upd_V  + (size_t)i * D * D,     pUV[i] + 16384,  128, 128);
        addjob(upd_w1 + (size_t)i * 2 * D * D, pUpdW1[i], 256, 128);
        addjob(upd_w2 + (size_t)i * D * D3,    pUpdW2[i], 128, 384);
    }
    k_packall<<<bacc, 256, 0, stream>>>(jobs);
    k_packrbf<<<18, 256, 0, stream>>>(rbf_w, rbf_b, pRbfAll);

    // ---- edge sort precompute (once per launch) ----
    hipMemsetAsync(cnt, 0, (size_t)N_NODES * 4, stream);
    k_hist<<<(N_EDGES + 255) / 256, 256, 0, stream>>>(edges, cnt);
    k_scan1<<<NCH, 512, 0, stream>>>(cnt, csum);
    k_scan2<<<1, 64, 0, stream>>>(csum, cbase);
    k_scan3<<<NCH, 512, 0, stream>>>(cnt, cbase, rowptr);
    hipMemsetAsync(cnt, 0, (size_t)N_NODES * 4, stream);  // reuse as cursor
    k_scatter<<<(N_EDGES + 255) / 256, 256, 0, stream>>>(edges, r_ij, rhat, rowptr, cnt,
                                                         esrc, erbf, erhat);

    // ---- state init ----
    hipMemsetAsync(bufV0, 0, (size_t)N_NODES * D3 * 2, stream);
    hipMemsetAsync(d_out, 0, (size_t)out_size * sizeof(float), stream);
    k_embed<<<(N_NODES * D) / 256, 256, 0, stream>>>(z, emb, s);

    const int gN  = gemm_grid(N_NODES);
    const int gN3 = gemm_grid(N_NODES * 3);

    for (int i = 0; i < 3; ++i) {
        short* vstate = (i & 1) ? bufV1 : bufV0;   // current v (bf16)
        short* vscr   = (i & 1) ? bufV0 : bufV1;   // next v
        // h = silu(s @ msg_w1 + b1)
        k_gemm<128, 128, true, 1><<<gN, 256, 0, stream>>>(
            s, nullptr, pMsgW1[i], msg_b1 + (size_t)i * D, hbuf, N_NODES);
        // s_pass = h @ msg_w2 + b2
        k_gemm<128, 384, false, 0><<<gN, 256, 0, stream>>>(
            hbuf, nullptr, pMsgW2[i], msg_b2 + (size_t)i * D3, shrd, N_NODES);
        // segment-sum edge gather with MFMA gates: s += ds ; vscr = vstate + dv
        k_edge3<<<4096, 128, 0, stream>>>(rowptr, esrc, erbf, erhat,
                                          pRbfAll + (size_t)i * 12288,
                                          shrd, vstate, s, vscr);
        // Uv (into dead vstate buffer) and Vv in ONE GEMM (single A read)
        k_gemmUV<<<gN3, 256, 0, stream>>>(vscr, pUV[i], vstate, Vv, N_NODES * 3);
        // V_norm (into shrd; s_pass dead now)
        k_svbuild<<<(N_NODES * D) / 256, 256, 0, stream>>>(Vv, Vn);
        // h2 = silu([Vn | s] @ upd_w1 + b1)
        k_gemm<256, 128, true, 2><<<gN, 256, 0, stream>>>(
            Vn, s, pUpdW1[i], upd_b1 + (size_t)i * D, hbuf, N_NODES);
        // a = h2 @ upd_w2 + b2  (clobbers shrd incl. Vn region — Vn already consumed)
        k_gemm<128, 384, false, 0><<<gN, 256, 0, stream>>>(
            hbuf, nullptr, pUpdW2[i], upd_b2 + (size_t)i * D3, shrd, N_NODES);
        // gated update of s and v (in place on vscr)
        k_apply<<<(N_NODES * D) / 256, 256, 0, stream>>>(s, vscr, vstate, Vv, shrd);
    }

    // readout
    k_gemm<128, 128, true, 1><<<gN, 256, 0, stream>>>(
        s, nullptr, pBlue, blue_b1, hbuf, N_NODES);
    k_blue_dot<<<N_NODES / 2, 256, 0, stream>>>(hbuf, graph_idx, blue_w2, blue_b2, out);
}